// Round 13
// baseline (151.748 us; speedup 1.0000x reference)
//
#include <hip/hip_runtime.h>

#define NN 8000
#define NPAD 8064
#define NE 64000
#define INF 16
#define HH 128
#define MM 16
#define EDF 4
#define OUTF 4
#define NL 2
#define BN_EPS 1e-5f
#define BPR 2080          // Bp rows per layer: 2048 qn + 16 b2 + 16 rootW
#define CAP 48            // per-node edge bucket capacity

typedef __attribute__((ext_vector_type(8))) short short8;
typedef __attribute__((ext_vector_type(4))) float f32x4;

static __device__ __forceinline__ unsigned short f2bf(float f) {
  unsigned u = __builtin_bit_cast(unsigned, f);
  u = (u + 0x7fffu + ((u >> 16) & 1u)) >> 16;
  return (unsigned short)u;
}
static __device__ __forceinline__ float bf2f(unsigned short s) {
  unsigned u = ((unsigned)s) << 16;
  return __builtin_bit_cast(float, u);
}

// bijective k-permutation for contract LDS layout, and its inverse
static __device__ __forceinline__ int qperm(int k) {
  return ((k >> 3) & 3) | ((k & 7) << 2) | (k & 0x60);
}
static __device__ __forceinline__ int qinv(int r) {
  return ((r & 3) << 3) | ((r >> 2) & 7) | (r & 0x60);
}

// in_proj (all blocks) + edge bucket-scatter (0..499, src bucket + dst pos index)
// + Bp build (500..759 both layers)
__global__ __launch_bounds__(128) void front_k(
    const float* __restrict__ x, const float* __restrict__ inW,
    const float* __restrict__ inb, const int* __restrict__ ei,
    const float* __restrict__ ea,
    const float* __restrict__ W2, const float* __restrict__ b2,
    const float* __restrict__ rW,
    unsigned short* __restrict__ hb,
    int* __restrict__ cnt, int* __restrict__ cntd,
    unsigned short* __restrict__ Bp,
    float* __restrict__ ea_s, int* __restrict__ pos_d) {
  int blk = blockIdx.x;
  int t = threadIdx.x;
  __shared__ float sx[INF];
  if (t < INF) sx[t] = x[blk * INF + t];
  __syncthreads();
  float acc = inb[t];
#pragma unroll
  for (int i = 0; i < INF; ++i) acc = fmaf(sx[i], inW[i * HH + t], acc);
  hb[(size_t)blk * HH + t] = f2bf(acc);

  if (blk < 500) {
    int e = blk * 128 + t;
    int src = ei[e], dst = ei[NE + e];
    int slot = atomicAdd(&cnt[src], 1);
    int p = src * CAP + slot;
    *(float4*)&ea_s[(size_t)p * 4] = *(const float4*)&ea[(size_t)e * 4];
    int slotd = atomicAdd(&cntd[dst], 1);
    pos_d[dst * CAP + slotd] = p;
  } else if (blk < 756) {
    // transpose one W2 row k: read 2048 f32 contiguous, write 16 Bp rows coalesced
    int r = blk - 500;            // 0..255
    int l = r >> 7, k = r & 127;
    const float* w2row = W2 + (size_t)l * (HH * HH * MM) + (size_t)k * 2048;
    float4 v0 = *(const float4*)&w2row[t * 16 + 0];
    float4 v1 = *(const float4*)&w2row[t * 16 + 4];
    float4 v2 = *(const float4*)&w2row[t * 16 + 8];
    float4 v3 = *(const float4*)&w2row[t * 16 + 12];
    unsigned short* bpr = Bp + ((size_t)l * BPR + (size_t)k * 16) * HH + t;
#pragma unroll
    for (int j = 0; j < 4; ++j) bpr[(0 + j) * HH] = f2bf((&v0.x)[j]);
#pragma unroll
    for (int j = 0; j < 4; ++j) bpr[(4 + j) * HH] = f2bf((&v1.x)[j]);
#pragma unroll
    for (int j = 0; j < 4; ++j) bpr[(8 + j) * HH] = f2bf((&v2.x)[j]);
#pragma unroll
    for (int j = 0; j < 4; ++j) bpr[(12 + j) * HH] = f2bf((&v3.x)[j]);
  } else if (blk < 760) {
    // b2 rows (756,757) at Bp row 2048; rootW rows (758,759) at Bp row 2064
    int isroot = (blk >= 758);
    int l = (blk - 756) & 1;
    const float* src = isroot ? (rW + (size_t)l * HH * MM) : (b2 + (size_t)l * 2048);
    float4 v0 = *(const float4*)&src[t * 16 + 0];
    float4 v1 = *(const float4*)&src[t * 16 + 4];
    float4 v2 = *(const float4*)&src[t * 16 + 8];
    float4 v3 = *(const float4*)&src[t * 16 + 12];
    unsigned short* bpr = Bp + ((size_t)l * BPR + 2048 + isroot * 16) * HH + t;
#pragma unroll
    for (int j = 0; j < 4; ++j) bpr[(0 + j) * HH] = f2bf((&v0.x)[j]);
#pragma unroll
    for (int j = 0; j < 4; ++j) bpr[(4 + j) * HH] = f2bf((&v1.x)[j]);
#pragma unroll
    for (int j = 0; j < 4; ++j) bpr[(8 + j) * HH] = f2bf((&v2.x)[j]);
#pragma unroll
    for (int j = 0; j < 4; ++j) bpr[(12 + j) * HH] = f2bf((&v3.x)[j]);
  }
}

// Qn[NPAD x 2048](bf16) = A[NPAD x 128] @ Bp^T ; grid (9, 63).
// A staged once per block; bn<8 -> 2 Qn chunks; bn==8 -> B2 + Xroot (f32).
__global__ __launch_bounds__(256) void gemm_qn_k(
    const unsigned short* __restrict__ hb, const float* __restrict__ hpre,
    const float* __restrict__ bnsums, const float* __restrict__ gamma,
    const float* __restrict__ beta, int bn_mode,
    const unsigned short* __restrict__ Bp,
    unsigned short* __restrict__ Qn, float* __restrict__ B2,
    float* __restrict__ Xroot) {
  __shared__ unsigned short sA[16384];
  __shared__ unsigned short sB[16384];
  int tid = threadIdx.x;
  int bm = blockIdx.y, bn = blockIdx.x;
  int r0 = bm * 128;

  // ---- A staging (once per block) ----
  if (bn_mode == 0) {
#pragma unroll
    for (int rr = 0; rr < 8; ++rr) {
      int s = rr * 256 + tid;
      int row = s >> 4, k8 = s & 15;
      int n = r0 + row;
      uint4 v = make_uint4(0, 0, 0, 0);
      if (n < NN) v = *(const uint4*)&hb[(size_t)n * HH + k8 * 8];
      *(uint4*)&sA[(s ^ ((s >> 4) & 7)) * 8] = v;
    }
  } else {
    int k8 = tid & 15;
    int c0 = k8 * 8;
    float scl[8], shf[8];
#pragma unroll
    for (int j = 0; j < 8; ++j) {
      int c = c0 + j;
      float mu = bnsums[c] * (1.0f / NN);
      float var = bnsums[HH + c] * (1.0f / NN) - mu * mu;
      float sc = gamma[c] * rsqrtf(var + BN_EPS);
      scl[j] = sc;
      shf[j] = beta[c] - mu * sc;
    }
#pragma unroll
    for (int rr = 0; rr < 8; ++rr) {
      int s = rr * 256 + tid;
      int row = s >> 4;
      int n = r0 + row;
      short8 o = {0, 0, 0, 0, 0, 0, 0, 0};
      if (n < NN) {
        float4 v0 = *(const float4*)&hpre[(size_t)n * HH + c0];
        float4 v1 = *(const float4*)&hpre[(size_t)n * HH + c0 + 4];
#pragma unroll
        for (int j = 0; j < 4; ++j) {
          o[j] = (short)f2bf(fmaxf(0.f, fmaf((&v0.x)[j], scl[j], shf[j])));
          o[4 + j] = (short)f2bf(fmaxf(0.f, fmaf((&v1.x)[j], scl[4 + j], shf[4 + j])));
        }
      }
      *(short8*)&sA[(s ^ ((s >> 4) & 7)) * 8] = o;
    }
  }

  int wid = tid >> 6, lane = tid & 63;
  int wr = (wid >> 1) * 64;
  int wc = (wid & 1) * 64;
  int l15 = lane & 15, l4 = lane >> 4;

  int nchunk = (bn < 8) ? 2 : 1;
  for (int half = 0; half < nchunk; ++half) {
    int chunk = (bn < 8) ? (bn * 2 + half) : 16;

    if (chunk < 16) {
      const uint4* gB = (const uint4*)(Bp + (size_t)chunk * 128 * HH);
#pragma unroll
      for (int rr = 0; rr < 8; ++rr) {
        int s = rr * 256 + tid;
        uint4 v = gB[s];
        *(uint4*)&sB[(s ^ ((s >> 4) & 7)) * 8] = v;
      }
    } else {
      const uint4* gB = (const uint4*)(Bp + (size_t)2048 * HH);
#pragma unroll
      for (int rr = 0; rr < 8; ++rr) {
        int s = rr * 256 + tid;
        int row = s >> 4;
        uint4 v = make_uint4(0, 0, 0, 0);
        if (row < 32) v = gB[s];
        *(uint4*)&sB[(s ^ ((s >> 4) & 7)) * 8] = v;
      }
    }
    __syncthreads();

    f32x4 acc[4][4] = {};
#pragma unroll
    for (int ks = 0; ks < 4; ++ks) {
      short8 af[4], bfr[4];
      int kb = ks * 4 + l4;
#pragma unroll
      for (int mr = 0; mr < 4; ++mr) {
        int r = wr + mr * 16 + l15;
        af[mr] = *(const short8*)&sA[(r * 16 + (kb ^ (r & 7))) * 8];
      }
#pragma unroll
      for (int nc = 0; nc < 4; ++nc) {
        int r = wc + nc * 16 + l15;
        bfr[nc] = *(const short8*)&sB[(r * 16 + (kb ^ (r & 7))) * 8];
      }
#pragma unroll
      for (int mr = 0; mr < 4; ++mr)
#pragma unroll
        for (int nc = 0; nc < 4; ++nc)
          acc[mr][nc] = __builtin_amdgcn_mfma_f32_16x16x32_bf16(af[mr], bfr[nc], acc[mr][nc], 0, 0, 0);
    }

    if (chunk < 16) {
#pragma unroll
      for (int mr = 0; mr < 4; ++mr) {
        int rr0 = r0 + wr + mr * 16 + l4 * 4;
#pragma unroll
        for (int nc = 0; nc < 4; ++nc) {
          int c0 = chunk * 128 + wc + nc * 16 + l15;
#pragma unroll
          for (int j = 0; j < 4; ++j)
            Qn[(size_t)(rr0 + j) * (HH * MM) + c0] = f2bf(acc[mr][nc][j]);
        }
      }
    } else if (wc == 0) {
#pragma unroll
      for (int mr = 0; mr < 4; ++mr) {
        int rr0 = r0 + wr + mr * 16 + l4 * 4;
#pragma unroll
        for (int j = 0; j < 4; ++j) {
          B2[(size_t)(rr0 + j) * MM + l15] = acc[mr][0][j];
          Xroot[(size_t)(rr0 + j) * MM + l15] = acc[mr][1][j];
        }
      }
    }
    __syncthreads();
  }
}

// One wave per src node: P[d x 16] = relu1[d x 128] @ Qn[n][128 x 16] via MFMA.
// NO atomics: stores messages (+B2) to the src-ordered bucket with plain stores.
__global__ __launch_bounds__(256) void contract_k(const float* __restrict__ ea_s,
                                                  const int* __restrict__ cnt,
                                                  const float* __restrict__ W1,
                                                  const float* __restrict__ b1,
                                                  const unsigned short* __restrict__ Qn,
                                                  const float* __restrict__ B2,
                                                  float* __restrict__ P) {
  __shared__ float sW1[EDF * HH];
  __shared__ float sb1[HH];
  __shared__ unsigned short sQ[4][HH * MM];
  int tid = threadIdx.x;
  for (int i = tid; i < EDF * HH; i += 256) sW1[i] = W1[i];
  if (tid < HH) sb1[tid] = b1[tid];
  __syncthreads();

  int wid = tid >> 6, lane = tid & 63;
  int n = blockIdx.x * 4 + wid;
  int l15 = lane & 15, l4 = lane >> 4;
  int count = cnt[n];
  if (count == 0) return;

  {
    const unsigned short* q = Qn + (size_t)n * (HH * MM);
#pragma unroll
    for (int i = 0; i < 4; ++i) {
      int r = i * 32 + (lane >> 1);
      int c = (lane & 1) * 8;
      uint4 v = *(const uint4*)(q + qinv(r) * 16 + c);
      *(uint4*)&sQ[wid][i * 512 + lane * 8] = v;
    }
  }
  float b2v = B2[(size_t)n * MM + l15];
  __builtin_amdgcn_s_waitcnt(0);

  const float* eab = ea_s + (size_t)n * CAP * 4;
  float* Pn = P + (size_t)n * CAP * MM;
  for (int t0 = 0; t0 < count; t0 += 16) {
    int rr = t0 + l15;
    bool valid = rr < count;
    float4 eav = valid ? *(const float4*)&eab[(size_t)rr * 4]
                       : make_float4(0.f, 0.f, 0.f, 0.f);
    f32x4 acc = {0.f, 0.f, 0.f, 0.f};
#pragma unroll
    for (int ks = 0; ks < 4; ++ks) {
      short8 a, b;
#pragma unroll
      for (int j = 0; j < 8; ++j) {
        int k = ks * 32 + l4 * 8 + j;
        float r = fmaf(eav.w, sW1[3 * HH + k],
                   fmaf(eav.z, sW1[2 * HH + k],
                     fmaf(eav.y, sW1[HH + k], fmaf(eav.x, sW1[k], sb1[k]))));
        a[j] = valid ? (short)f2bf(fmaxf(r, 0.f)) : (short)0;
        b[j] = (short)sQ[wid][qperm(k) * 16 + l15];
      }
      acc = __builtin_amdgcn_mfma_f32_16x16x32_bf16(a, b, acc, 0, 0, 0);
    }
#pragma unroll
    for (int j = 0; j < 4; ++j) {
      int r = t0 + l4 * 4 + j;
      if (r < count) Pn[(size_t)r * MM + l15] = acc[j] + b2v;
    }
  }
}

// 16 nodes/block: gather-sum incoming P rows (no atomics upstream);
// xm = mean + Xroot + cbias ; hp = resid + xm@msgW + msgb ; fused BN partials.
__global__ __launch_bounds__(256) void node_update_k(
    const unsigned short* __restrict__ hb, const float* __restrict__ hsrc_pre,
    const float* __restrict__ bnsums, const float* __restrict__ gamma,
    const float* __restrict__ beta, int bn_mode,
    const float* __restrict__ P, const int* __restrict__ pos_d,
    const int* __restrict__ cntd,
    const float* __restrict__ Xroot, const float* __restrict__ cbias,
    const float* __restrict__ msgW, const float* __restrict__ msgb,
    float* __restrict__ hpre, float* __restrict__ sums) {
  __shared__ float smw[MM * HH];
  __shared__ float xm[16][MM];
  __shared__ float scb[MM];
  __shared__ float smb[HH];
  __shared__ float red[256];
  __shared__ float sscl[HH], sshf[HH];
  int tid = threadIdx.x;
  int n0 = blockIdx.x * 16;
  for (int i = tid; i < MM * HH; i += 256) smw[i] = msgW[i];
  if (tid < MM) scb[tid] = cbias[tid];
  if (tid < HH) smb[tid] = msgb[tid];
  if (bn_mode && tid < HH) {
    float mu = bnsums[tid] * (1.0f / NN);
    float var = bnsums[HH + tid] * (1.0f / NN) - mu * mu;
    float sc = gamma[tid] * rsqrtf(var + BN_EPS);
    sscl[tid] = sc;
    sshf[tid] = beta[tid] - mu * sc;
  }
  __syncthreads();

  {
    int ni = tid >> 4, m = tid & 15;
    int n = n0 + ni;
    int dcount = cntd[n];
    const int* pd = pos_d + (size_t)n * CAP;
    float s = 0.f;
    for (int i = 0; i < dcount; ++i) s += P[(size_t)pd[i] * MM + m];
    xm[ni][m] = s / fmaxf((float)dcount, 1.0f) + Xroot[(size_t)n * MM + m] + scb[m];
  }
  __syncthreads();

  int t = tid & 127;
  float lsum = 0.f, lss = 0.f;
#pragma unroll
  for (int pass = 0; pass < 8; ++pass) {
    int ni = pass * 2 + (tid >> 7);
    size_t idx = (size_t)(n0 + ni) * HH + t;
    float resid;
    if (bn_mode) {
      resid = fmaxf(0.f, fmaf(hsrc_pre[idx], sscl[t], sshf[t]));
    } else {
      resid = bf2f(hb[idx]);
    }
    float hp = resid + smb[t];
#pragma unroll
    for (int m = 0; m < MM; ++m) hp = fmaf(xm[ni][m], smw[m * HH + t], hp);
    hpre[idx] = hp;
    lsum += hp;
    lss = fmaf(hp, hp, lss);
  }
  red[tid] = lsum;
  __syncthreads();
  if (tid < 128) atomicAdd(&sums[t], red[tid] + red[tid + 128]);
  __syncthreads();
  red[tid] = lss;
  __syncthreads();
  if (tid < 128) atomicAdd(&sums[HH + t], red[tid] + red[tid + 128]);
}

__global__ void out_proj_k(const float* __restrict__ hpre,
                           const float* __restrict__ bnsums,
                           const float* __restrict__ gamma,
                           const float* __restrict__ beta,
                           const float* __restrict__ W, const float* __restrict__ b,
                           float* __restrict__ out) {
  __shared__ float sscl[HH], sshf[HH];
  int tid = threadIdx.x;
  if (tid < HH) {
    float mu = bnsums[tid] * (1.0f / NN);
    float var = bnsums[HH + tid] * (1.0f / NN) - mu * mu;
    float sc = gamma[tid] * rsqrtf(var + BN_EPS);
    sscl[tid] = sc;
    sshf[tid] = beta[tid] - mu * sc;
  }
  __syncthreads();
  int n = blockIdx.x * 4 + (tid >> 6);
  int lane = tid & 63;
  if (n >= NN) return;
  float acc0 = 0.f, acc1 = 0.f, acc2 = 0.f, acc3 = 0.f;
#pragma unroll
  for (int rep = 0; rep < 2; ++rep) {
    int hh = lane + rep * 64;
    float hv = fmaxf(0.f, fmaf(hpre[(size_t)n * HH + hh], sscl[hh], sshf[hh]));
    acc0 = fmaf(hv, W[hh * OUTF + 0], acc0);
    acc1 = fmaf(hv, W[hh * OUTF + 1], acc1);
    acc2 = fmaf(hv, W[hh * OUTF + 2], acc2);
    acc3 = fmaf(hv, W[hh * OUTF + 3], acc3);
  }
#pragma unroll
  for (int s = 32; s > 0; s >>= 1) {
    acc0 += __shfl_down(acc0, s);
    acc1 += __shfl_down(acc1, s);
    acc2 += __shfl_down(acc2, s);
    acc3 += __shfl_down(acc3, s);
  }
  if (lane == 0) {
    out[n * OUTF + 0] = acc0 + b[0];
    out[n * OUTF + 1] = acc1 + b[1];
    out[n * OUTF + 2] = acc2 + b[2];
    out[n * OUTF + 3] = acc3 + b[3];
  }
}

extern "C" void kernel_launch(void* const* d_in, const int* in_sizes, int n_in,
                              void* d_out, int out_size, void* d_ws, size_t ws_size,
                              hipStream_t stream) {
  (void)in_sizes; (void)n_in; (void)out_size; (void)ws_size;
  const float* x    = (const float*)d_in[0];
  const int* ei     = (const int*)d_in[1];
  const float* ea   = (const float*)d_in[2];
  const float* inW  = (const float*)d_in[3];
  const float* inb  = (const float*)d_in[4];
  const float* cW1  = (const float*)d_in[5];
  const float* cb1  = (const float*)d_in[6];
  const float* cW2  = (const float*)d_in[7];
  const float* cb2  = (const float*)d_in[8];
  const float* rW   = (const float*)d_in[9];
  const float* cbias= (const float*)d_in[10];
  const float* gam  = (const float*)d_in[11];
  const float* bet  = (const float*)d_in[12];
  const float* mW   = (const float*)d_in[13];
  const float* mb   = (const float*)d_in[14];
  const float* oW   = (const float*)d_in[15];
  const float* ob   = (const float*)d_in[16];
  float* out = (float*)d_out;

  float* ws = (float*)d_ws;
  size_t off = 0;
  // contiguous zero region: cnt, cntd, sums0, sums1 (one small memset)
  int* cnt     = (int*)(ws + off); off += 8192;
  int* cntd    = (int*)(ws + off); off += 8192;
  float* sums0 = ws + off; off += 256;
  float* sums1 = ws + off; off += 256;
  size_t zero_floats = off;
  float* hpre0 = ws + off; off += (size_t)NN * HH;
  float* hpre1 = ws + off; off += (size_t)NN * HH;
  float* B2    = ws + off; off += (size_t)NPAD * MM;
  float* Xroot = ws + off; off += (size_t)NPAD * MM;
  float* P     = ws + off; off += (size_t)NN * CAP * MM;
  unsigned short* hb = (unsigned short*)(ws + off); off += (size_t)NN * HH / 2;
  unsigned short* Bp = (unsigned short*)(ws + off); off += (size_t)NL * BPR * HH / 2;
  unsigned short* Qn = (unsigned short*)(ws + off); off += (size_t)NPAD * HH * MM / 2;
  float* ea_s  = ws + off; off += (size_t)NN * CAP * 4;
  int* pos_d   = (int*)(ws + off); off += (size_t)NN * CAP;

  hipMemsetAsync(cnt, 0, zero_floats * sizeof(float), stream);
  front_k<<<NN, 128, 0, stream>>>(x, inW, inb, ei, ea, cW2, cb2, rW, hb,
                                  cnt, cntd, Bp, ea_s, pos_d);

  dim3 gg(9, NPAD / 128);
  // ---- layer 0 ----
  gemm_qn_k<<<gg, 256, 0, stream>>>(hb, hpre0, sums0, gam, bet, 0, Bp, Qn, B2, Xroot);
  contract_k<<<NN / 4, 256, 0, stream>>>(ea_s, cnt, cW1, cb1, Qn, B2, P);
  node_update_k<<<NN / 16, 256, 0, stream>>>(hb, hpre0, sums0, gam, bet, 0,
                                             P, pos_d, cntd, Xroot, cbias, mW, mb,
                                             hpre0, sums0);
  // ---- layer 1 ----
  gemm_qn_k<<<gg, 256, 0, stream>>>(hb, hpre0, sums0, gam, bet, 1,
                                    Bp + (size_t)BPR * HH, Qn, B2, Xroot);
  contract_k<<<NN / 4, 256, 0, stream>>>(ea_s, cnt, cW1 + EDF * HH, cb1 + HH,
                                         Qn, B2, P);
  node_update_k<<<NN / 16, 256, 0, stream>>>(hb, hpre0, sums0, gam, bet, 1,
                                             P, pos_d, cntd, Xroot, cbias + MM,
                                             mW + MM * HH, mb + HH,
                                             hpre1, sums1);
  out_proj_k<<<NN / 4, 256, 0, stream>>>(hpre1, sums1, gam + HH, bet + HH,
                                         oW, ob, out);
}

// Round 14
// 144.103 us; speedup vs baseline: 1.0531x; 1.0531x over previous
//
#include <hip/hip_runtime.h>

#define NN 8000
#define NE 64000
#define INF 16
#define HH 128
#define MM 16
#define EDF 4
#define OUTF 4
#define NL 2
#define BN_EPS 1e-5f
#define BPR 2080          // Bp rows per layer: 2048 qn + 16 b2 + 16 rootW
#define CAP 48            // per-node edge bucket capacity
#define QS 2052           // sQ node stride in halfs

typedef __attribute__((ext_vector_type(8))) short short8;
typedef __attribute__((ext_vector_type(4))) float f32x4;

static __device__ __forceinline__ unsigned short f2bf(float f) {
  unsigned u = __builtin_bit_cast(unsigned, f);
  u = (u + 0x7fffu + ((u >> 16) & 1u)) >> 16;
  return (unsigned short)u;
}
static __device__ __forceinline__ float bf2f(unsigned short s) {
  unsigned u = ((unsigned)s) << 16;
  return __builtin_bit_cast(float, u);
}
static __device__ __forceinline__ int qperm(int k) {
  return ((k >> 3) & 3) | ((k & 7) << 2) | (k & 0x60);
}

// in_proj (all blocks) + edge bucket-scatter (0..499) + Bp build (500..759) + agg zero (760..884)
__global__ __launch_bounds__(128) void front_k(
    const float* __restrict__ x, const float* __restrict__ inW,
    const float* __restrict__ inb, const int* __restrict__ ei,
    const float* __restrict__ ea,
    const float* __restrict__ W2, const float* __restrict__ b2,
    const float* __restrict__ rW,
    unsigned short* __restrict__ hb,
    float* __restrict__ deg, int* __restrict__ cnt,
    unsigned short* __restrict__ Bp, float* __restrict__ agg,
    float* __restrict__ ea_s, int* __restrict__ dst_s) {
  int blk = blockIdx.x;
  int t = threadIdx.x;
  __shared__ float sx[INF];
  if (t < INF) sx[t] = x[blk * INF + t];
  __syncthreads();
  float acc = inb[t];
#pragma unroll
  for (int i = 0; i < INF; ++i) acc = fmaf(sx[i], inW[i * HH + t], acc);
  hb[(size_t)blk * HH + t] = f2bf(acc);

  if (blk < 500) {
    int e = blk * 128 + t;
    int src = ei[e], dst = ei[NE + e];
    atomicAdd(&deg[dst], 1.0f);
    int slot = atomicAdd(&cnt[src], 1);
    int p = src * CAP + slot;
    *(float4*)&ea_s[(size_t)p * 4] = *(const float4*)&ea[(size_t)e * 4];
    dst_s[p] = dst;
  } else if (blk < 756) {
    int r = blk - 500;            // 0..255
    int l = r >> 7, k = r & 127;
    const float* w2row = W2 + (size_t)l * (HH * HH * MM) + (size_t)k * 2048;
    float4 v0 = *(const float4*)&w2row[t * 16 + 0];
    float4 v1 = *(const float4*)&w2row[t * 16 + 4];
    float4 v2 = *(const float4*)&w2row[t * 16 + 8];
    float4 v3 = *(const float4*)&w2row[t * 16 + 12];
    unsigned short* bpr = Bp + ((size_t)l * BPR + (size_t)k * 16) * HH + t;
#pragma unroll
    for (int j = 0; j < 4; ++j) bpr[(0 + j) * HH] = f2bf((&v0.x)[j]);
#pragma unroll
    for (int j = 0; j < 4; ++j) bpr[(4 + j) * HH] = f2bf((&v1.x)[j]);
#pragma unroll
    for (int j = 0; j < 4; ++j) bpr[(8 + j) * HH] = f2bf((&v2.x)[j]);
#pragma unroll
    for (int j = 0; j < 4; ++j) bpr[(12 + j) * HH] = f2bf((&v3.x)[j]);
  } else if (blk < 760) {
    int isroot = (blk >= 758);
    int l = (blk - 756) & 1;
    const float* src = isroot ? (rW + (size_t)l * HH * MM) : (b2 + (size_t)l * 2048);
    float4 v0 = *(const float4*)&src[t * 16 + 0];
    float4 v1 = *(const float4*)&src[t * 16 + 4];
    float4 v2 = *(const float4*)&src[t * 16 + 8];
    float4 v3 = *(const float4*)&src[t * 16 + 12];
    unsigned short* bpr = Bp + ((size_t)l * BPR + 2048 + isroot * 16) * HH + t;
#pragma unroll
    for (int j = 0; j < 4; ++j) bpr[(0 + j) * HH] = f2bf((&v0.x)[j]);
#pragma unroll
    for (int j = 0; j < 4; ++j) bpr[(4 + j) * HH] = f2bf((&v1.x)[j]);
#pragma unroll
    for (int j = 0; j < 4; ++j) bpr[(8 + j) * HH] = f2bf((&v2.x)[j]);
#pragma unroll
    for (int j = 0; j < 4; ++j) bpr[(12 + j) * HH] = f2bf((&v3.x)[j]);
  } else if (blk < 885) {
    int i = (blk - 760) * 256 + t;
    uint4 z = make_uint4(0, 0, 0, 0);
    ((uint4*)agg)[i] = z;
    ((uint4*)agg)[i + 128] = z;
  }
}

// Fused layer: per block (512 thr), 16 src nodes.
// Phase 1 (hand-pipelined, 4-deep): Qn_tile[16x2048] = A[16x128] @ Bp^T -> LDS;
//   wave 7 computes B2 ctile (LDS), wave 6 computes Xroot ctile (global).
// Phase 2: per-node edge contraction P = relu1 @ Qn_tile[node], atomics into agg.
__global__ __launch_bounds__(512, 4) void fused_layer_k(
    const unsigned short* __restrict__ hb, const float* __restrict__ hpre,
    const float* __restrict__ bnsums, const float* __restrict__ gamma,
    const float* __restrict__ beta, int bn_mode,
    const unsigned short* __restrict__ Bp,
    const float* __restrict__ ea_s, const int* __restrict__ dst_s,
    const int* __restrict__ cnt, const float* __restrict__ W1,
    const float* __restrict__ b1, float* __restrict__ agg,
    float* __restrict__ Xroot) {
  __shared__ unsigned short sA[16 * 136];
  __shared__ unsigned short sQ[16 * QS];
  __shared__ float sW1[EDF * HH];
  __shared__ float sb1[HH];
  __shared__ float sB2[16][17];
  __shared__ float sscl[HH], sshf[HH];

  int tid = threadIdx.x;
  int n0 = blockIdx.x * 16;
  int wid = tid >> 6, lane = tid & 63;
  int l15 = lane & 15, l4 = lane >> 4;

  for (int i = tid; i < EDF * HH; i += 512) sW1[i] = W1[i];
  if (tid < HH) sb1[tid] = b1[tid];
  if (bn_mode && tid < HH) {
    float mu = bnsums[tid] * (1.0f / NN);
    float var = bnsums[HH + tid] * (1.0f / NN) - mu * mu;
    float sc = gamma[tid] * rsqrtf(var + BN_EPS);
    sscl[tid] = sc;
    sshf[tid] = beta[tid] - mu * sc;
  }
  __syncthreads();

  // stage A tile (threads 0..255): node tid>>4, 8 halfs at col (tid&15)*8
  if (tid < 256) {
    int node = tid >> 4, c0 = (tid & 15) * 8;
    if (bn_mode == 0) {
      uint4 v = *(const uint4*)&hb[(size_t)(n0 + node) * HH + c0];
      *(uint4*)&sA[node * 136 + c0] = v;
    } else {
      float4 v0 = *(const float4*)&hpre[(size_t)(n0 + node) * HH + c0];
      float4 v1 = *(const float4*)&hpre[(size_t)(n0 + node) * HH + c0 + 4];
      short8 o;
#pragma unroll
      for (int j = 0; j < 4; ++j) {
        o[j] = (short)f2bf(fmaxf(0.f, fmaf((&v0.x)[j], sscl[c0 + j], sshf[c0 + j])));
        o[4 + j] = (short)f2bf(fmaxf(0.f, fmaf((&v1.x)[j], sscl[c0 + 4 + j], sshf[c0 + 4 + j])));
      }
      *(short8*)&sA[node * 136 + c0] = o;
    }
  }
  __syncthreads();

  short8 A0 = *(const short8*)&sA[l15 * 136 + 0 * 32 + l4 * 8];
  short8 A1 = *(const short8*)&sA[l15 * 136 + 1 * 32 + l4 * 8];
  short8 A2 = *(const short8*)&sA[l15 * 136 + 2 * 32 + l4 * 8];
  short8 A3 = *(const short8*)&sA[l15 * 136 + 3 * 32 + l4 * 8];

  // ---- GEMM phase: wave handles ctiles [wid*16, wid*16+16), 4-deep pipeline ----
  int ctb = wid * 16;

#define LDB(v0, v1, v2, v3, CT)                                               \
  do {                                                                        \
    const unsigned short* p_ = Bp + ((size_t)((CT) * 16 + l15)) * HH + l4 * 8;\
    v0 = *(const short8*)(p_);                                                \
    v1 = *(const short8*)(p_ + 32);                                           \
    v2 = *(const short8*)(p_ + 64);                                           \
    v3 = *(const short8*)(p_ + 96);                                           \
  } while (0)

  short8 b00, b01, b02, b03, b10, b11, b12, b13;
  short8 b20, b21, b22, b23, b30, b31, b32, b33;
  LDB(b00, b01, b02, b03, ctb + 0);
  LDB(b10, b11, b12, b13, ctb + 1);
  LDB(b20, b21, b22, b23, ctb + 2);
  LDB(b30, b31, b32, b33, ctb + 3);

#define STAGE(v0, v1, v2, v3, I)                                              \
  do {                                                                        \
    int ct_ = ctb + (I);                                                      \
    f32x4 acc_ = {0.f, 0.f, 0.f, 0.f};                                        \
    acc_ = __builtin_amdgcn_mfma_f32_16x16x32_bf16(A0, v0, acc_, 0, 0, 0);    \
    acc_ = __builtin_amdgcn_mfma_f32_16x16x32_bf16(A1, v1, acc_, 0, 0, 0);    \
    acc_ = __builtin_amdgcn_mfma_f32_16x16x32_bf16(A2, v2, acc_, 0, 0, 0);    \
    acc_ = __builtin_amdgcn_mfma_f32_16x16x32_bf16(A3, v3, acc_, 0, 0, 0);    \
    int kq_ = qperm(ct_) * 16 + l15;                                          \
    sQ[(l4 * 4 + 0) * QS + kq_] = f2bf(acc_[0]);                              \
    sQ[(l4 * 4 + 1) * QS + kq_] = f2bf(acc_[1]);                              \
    sQ[(l4 * 4 + 2) * QS + kq_] = f2bf(acc_[2]);                              \
    sQ[(l4 * 4 + 3) * QS + kq_] = f2bf(acc_[3]);                              \
    if ((I) + 4 < 16) LDB(v0, v1, v2, v3, ct_ + 4);                           \
  } while (0)

  STAGE(b00, b01, b02, b03, 0);
  STAGE(b10, b11, b12, b13, 1);
  STAGE(b20, b21, b22, b23, 2);
  STAGE(b30, b31, b32, b33, 3);
  STAGE(b00, b01, b02, b03, 4);
  STAGE(b10, b11, b12, b13, 5);
  STAGE(b20, b21, b22, b23, 6);
  STAGE(b30, b31, b32, b33, 7);
  STAGE(b00, b01, b02, b03, 8);
  STAGE(b10, b11, b12, b13, 9);
  STAGE(b20, b21, b22, b23, 10);
  STAGE(b30, b31, b32, b33, 11);
  STAGE(b00, b01, b02, b03, 12);
  STAGE(b10, b11, b12, b13, 13);
  STAGE(b20, b21, b22, b23, 14);
  STAGE(b30, b31, b32, b33, 15);
#undef STAGE
#undef LDB

  // extra ctiles: wave 7 -> B2 (Bp rows 2048..2063, LDS); wave 6 -> Xroot (2064..2079, global)
  if (wid >= 6) {
    int base = (wid == 7) ? 2048 : 2064;
    const unsigned short* p = Bp + ((size_t)(base + l15)) * HH + l4 * 8;
    short8 c0 = *(const short8*)(p);
    short8 c1 = *(const short8*)(p + 32);
    short8 c2 = *(const short8*)(p + 64);
    short8 c3 = *(const short8*)(p + 96);
    f32x4 acc = {0.f, 0.f, 0.f, 0.f};
    acc = __builtin_amdgcn_mfma_f32_16x16x32_bf16(A0, c0, acc, 0, 0, 0);
    acc = __builtin_amdgcn_mfma_f32_16x16x32_bf16(A1, c1, acc, 0, 0, 0);
    acc = __builtin_amdgcn_mfma_f32_16x16x32_bf16(A2, c2, acc, 0, 0, 0);
    acc = __builtin_amdgcn_mfma_f32_16x16x32_bf16(A3, c3, acc, 0, 0, 0);
    if (wid == 7) {
#pragma unroll
      for (int j = 0; j < 4; ++j) sB2[l4 * 4 + j][l15] = acc[j];
    } else {
#pragma unroll
      for (int j = 0; j < 4; ++j)
        Xroot[(size_t)(n0 + l4 * 4 + j) * MM + l15] = acc[j];
    }
  }
  __syncthreads();

  // ---- Contract phase: wave handles nodes wid*2 + {0,1} ----
  for (int ni = 0; ni < 2; ++ni) {
    int nl = wid * 2 + ni;
    int n = n0 + nl;
    int count = cnt[n];
    if (count == 0) continue;

    short8 qb0, qb1, qb2, qb3;
#pragma unroll
    for (int j = 0; j < 8; ++j) {
      qb0[j] = (short)sQ[nl * QS + qperm(0 * 32 + l4 * 8 + j) * 16 + l15];
      qb1[j] = (short)sQ[nl * QS + qperm(1 * 32 + l4 * 8 + j) * 16 + l15];
      qb2[j] = (short)sQ[nl * QS + qperm(2 * 32 + l4 * 8 + j) * 16 + l15];
      qb3[j] = (short)sQ[nl * QS + qperm(3 * 32 + l4 * 8 + j) * 16 + l15];
    }
    float b2v = sB2[nl][l15];

    const float* eab = ea_s + (size_t)n * CAP * 4;
    const int* dsb = dst_s + (size_t)n * CAP;
    for (int t0 = 0; t0 < count; t0 += 16) {
      int rr = t0 + l15;
      bool valid = rr < count;
      float4 eav = valid ? *(const float4*)&eab[(size_t)rr * 4]
                         : make_float4(0.f, 0.f, 0.f, 0.f);
      f32x4 acc = {0.f, 0.f, 0.f, 0.f};
#pragma unroll
      for (int ks = 0; ks < 4; ++ks) {
        short8 a;
#pragma unroll
        for (int j = 0; j < 8; ++j) {
          int k = ks * 32 + l4 * 8 + j;
          float r = fmaf(eav.w, sW1[3 * HH + k],
                     fmaf(eav.z, sW1[2 * HH + k],
                       fmaf(eav.y, sW1[HH + k], fmaf(eav.x, sW1[k], sb1[k]))));
          a[j] = valid ? (short)f2bf(fmaxf(r, 0.f)) : (short)0;
        }
        short8 qb = (ks == 0) ? qb0 : (ks == 1) ? qb1 : (ks == 2) ? qb2 : qb3;
        acc = __builtin_amdgcn_mfma_f32_16x16x32_bf16(a, qb, acc, 0, 0, 0);
      }
#pragma unroll
      for (int j = 0; j < 4; ++j) {
        int r = t0 + l4 * 4 + j;
        if (r < count) {
          atomicAdd(&agg[(size_t)dsb[r] * MM + l15], acc[j] + b2v);
        }
      }
    }
  }
}

// 16 nodes/block: xm = agg/deg + Xroot + cbias ; hp = resid + xm@msgW + msgb
// fused BN partial sums; zeroes its agg slice for next layer.
__global__ __launch_bounds__(256) void node_update_k(
    const unsigned short* __restrict__ hb, const float* __restrict__ hsrc_pre,
    const float* __restrict__ bnsums, const float* __restrict__ gamma,
    const float* __restrict__ beta, int bn_mode,
    float* __restrict__ agg, const float* __restrict__ deg,
    const float* __restrict__ Xroot, const float* __restrict__ cbias,
    const float* __restrict__ msgW, const float* __restrict__ msgb,
    float* __restrict__ hpre, float* __restrict__ sums) {
  __shared__ float smw[MM * HH];
  __shared__ float xm[16][MM];
  __shared__ float scb[MM];
  __shared__ float smb[HH];
  __shared__ float red[256];
  __shared__ float sscl[HH], sshf[HH];
  int tid = threadIdx.x;
  int n0 = blockIdx.x * 16;
  for (int i = tid; i < MM * HH; i += 256) smw[i] = msgW[i];
  if (tid < MM) scb[tid] = cbias[tid];
  if (tid < HH) smb[tid] = msgb[tid];
  if (bn_mode && tid < HH) {
    float mu = bnsums[tid] * (1.0f / NN);
    float var = bnsums[HH + tid] * (1.0f / NN) - mu * mu;
    float sc = gamma[tid] * rsqrtf(var + BN_EPS);
    sscl[tid] = sc;
    sshf[tid] = beta[tid] - mu * sc;
  }
  __syncthreads();

  {
    int ni = tid >> 4, m = tid & 15;
    int n = n0 + ni;
    size_t idx = (size_t)n * MM + m;
    xm[ni][m] = agg[idx] / fmaxf(deg[n], 1.0f) + Xroot[idx] + scb[m];
  }
  __syncthreads();
  agg[(size_t)n0 * MM + tid] = 0.f;

  int t = tid & 127;
  float lsum = 0.f, lss = 0.f;
#pragma unroll
  for (int pass = 0; pass < 8; ++pass) {
    int ni = pass * 2 + (tid >> 7);
    size_t idx = (size_t)(n0 + ni) * HH + t;
    float resid;
    if (bn_mode) {
      resid = fmaxf(0.f, fmaf(hsrc_pre[idx], sscl[t], sshf[t]));
    } else {
      resid = bf2f(hb[idx]);
    }
    float hp = resid + smb[t];
#pragma unroll
    for (int m = 0; m < MM; ++m) hp = fmaf(xm[ni][m], smw[m * HH + t], hp);
    hpre[idx] = hp;
    lsum += hp;
    lss = fmaf(hp, hp, lss);
  }
  red[tid] = lsum;
  __syncthreads();
  if (tid < 128) atomicAdd(&sums[t], red[tid] + red[tid + 128]);
  __syncthreads();
  red[tid] = lss;
  __syncthreads();
  if (tid < 128) atomicAdd(&sums[HH + t], red[tid] + red[tid + 128]);
}

__global__ void out_proj_k(const float* __restrict__ hpre,
                           const float* __restrict__ bnsums,
                           const float* __restrict__ gamma,
                           const float* __restrict__ beta,
                           const float* __restrict__ W, const float* __restrict__ b,
                           float* __restrict__ out) {
  __shared__ float sscl[HH], sshf[HH];
  int tid = threadIdx.x;
  if (tid < HH) {
    float mu = bnsums[tid] * (1.0f / NN);
    float var = bnsums[HH + tid] * (1.0f / NN) - mu * mu;
    float sc = gamma[tid] * rsqrtf(var + BN_EPS);
    sscl[tid] = sc;
    sshf[tid] = beta[tid] - mu * sc;
  }
  __syncthreads();
  int n = blockIdx.x * 4 + (tid >> 6);
  int lane = tid & 63;
  if (n >= NN) return;
  float acc0 = 0.f, acc1 = 0.f, acc2 = 0.f, acc3 = 0.f;
#pragma unroll
  for (int rep = 0; rep < 2; ++rep) {
    int hh = lane + rep * 64;
    float hv = fmaxf(0.f, fmaf(hpre[(size_t)n * HH + hh], sscl[hh], sshf[hh]));
    acc0 = fmaf(hv, W[hh * OUTF + 0], acc0);
    acc1 = fmaf(hv, W[hh * OUTF + 1], acc1);
    acc2 = fmaf(hv, W[hh * OUTF + 2], acc2);
    acc3 = fmaf(hv, W[hh * OUTF + 3], acc3);
  }
#pragma unroll
  for (int s = 32; s > 0; s >>= 1) {
    acc0 += __shfl_down(acc0, s);
    acc1 += __shfl_down(acc1, s);
    acc2 += __shfl_down(acc2, s);
    acc3 += __shfl_down(acc3, s);
  }
  if (lane == 0) {
    out[n * OUTF + 0] = acc0 + b[0];
    out[n * OUTF + 1] = acc1 + b[1];
    out[n * OUTF + 2] = acc2 + b[2];
    out[n * OUTF + 3] = acc3 + b[3];
  }
}

extern "C" void kernel_launch(void* const* d_in, const int* in_sizes, int n_in,
                              void* d_out, int out_size, void* d_ws, size_t ws_size,
                              hipStream_t stream) {
  (void)in_sizes; (void)n_in; (void)out_size; (void)ws_size;
  const float* x    = (const float*)d_in[0];
  const int* ei     = (const int*)d_in[1];
  const float* ea   = (const float*)d_in[2];
  const float* inW  = (const float*)d_in[3];
  const float* inb  = (const float*)d_in[4];
  const float* cW1  = (const float*)d_in[5];
  const float* cb1  = (const float*)d_in[6];
  const float* cW2  = (const float*)d_in[7];
  const float* cb2  = (const float*)d_in[8];
  const float* rW   = (const float*)d_in[9];
  const float* cbias= (const float*)d_in[10];
  const float* gam  = (const float*)d_in[11];
  const float* bet  = (const float*)d_in[12];
  const float* mW   = (const float*)d_in[13];
  const float* mb   = (const float*)d_in[14];
  const float* oW   = (const float*)d_in[15];
  const float* ob   = (const float*)d_in[16];
  float* out = (float*)d_out;

  float* ws = (float*)d_ws;
  size_t off = 0;
  // contiguous zero region: deg, cnt, sums0, sums1 (one small memset)
  float* deg   = ws + off; off += 8192;
  int* cnt     = (int*)(ws + off); off += 8192;
  float* sums0 = ws + off; off += 256;
  float* sums1 = ws + off; off += 256;
  size_t zero_floats = off;
  float* agg   = ws + off; off += (size_t)NN * MM;      // zeroed by front_k
  float* hpre0 = ws + off; off += (size_t)NN * HH;
  float* hpre1 = ws + off; off += (size_t)NN * HH;
  float* Xroot = ws + off; off += (size_t)NN * MM;
  unsigned short* hb = (unsigned short*)(ws + off); off += (size_t)NN * HH / 2;
  unsigned short* Bp = (unsigned short*)(ws + off); off += (size_t)NL * BPR * HH / 2;
  float* ea_s  = ws + off; off += (size_t)NN * CAP * 4;
  int* dst_s   = (int*)(ws + off); off += (size_t)NN * CAP;

  hipMemsetAsync(deg, 0, zero_floats * sizeof(float), stream);
  front_k<<<NN, 128, 0, stream>>>(x, inW, inb, ei, ea, cW2, cb2, rW, hb,
                                  deg, cnt, Bp, agg, ea_s, dst_s);

  // ---- layer 0 ----
  fused_layer_k<<<NN / 16, 512, 0, stream>>>(hb, hpre0, sums0, gam, bet, 0,
                                             Bp, ea_s, dst_s, cnt, cW1, cb1,
                                             agg, Xroot);
  node_update_k<<<NN / 16, 256, 0, stream>>>(hb, hpre0, sums0, gam, bet, 0,
                                             agg, deg, Xroot, cbias, mW, mb,
                                             hpre0, sums0);
  // ---- layer 1 ----
  fused_layer_k<<<NN / 16, 512, 0, stream>>>(hb, hpre0, sums0, gam, bet, 1,
                                             Bp + (size_t)BPR * HH, ea_s, dst_s,
                                             cnt, cW1 + EDF * HH, cb1 + HH,
                                             agg, Xroot);
  node_update_k<<<NN / 16, 256, 0, stream>>>(hb, hpre0, sums0, gam, bet, 1,
                                             agg, deg, Xroot, cbias + MM,
                                             mW + MM * HH, mb + HH,
                                             hpre1, sums1);
  out_proj_k<<<NN / 4, 256, 0, stream>>>(hpre1, sums1, gam + HH, bet + HH,
                                         oW, ob, out);
}

// Round 15
// 133.652 us; speedup vs baseline: 1.1354x; 1.0782x over previous
//
#include <hip/hip_runtime.h>

#define NN 8000
#define NE 64000
#define INF 16
#define HH 128
#define MM 16
#define EDF 4
#define OUTF 4
#define NL 2
#define BN_EPS 1e-5f
#define BPR 2080          // Bp rows per layer: 2048 qn + 16 b2 + 16 rootW
#define CAP 48            // per-node edge bucket capacity
#define QS 2052           // sQ node stride in halfs

typedef __attribute__((ext_vector_type(8))) short short8;
typedef __attribute__((ext_vector_type(4))) float f32x4;

static __device__ __forceinline__ unsigned short f2bf(float f) {
  unsigned u = __builtin_bit_cast(unsigned, f);
  u = (u + 0x7fffu + ((u >> 16) & 1u)) >> 16;
  return (unsigned short)u;
}
static __device__ __forceinline__ float bf2f(unsigned short s) {
  unsigned u = ((unsigned)s) << 16;
  return __builtin_bit_cast(float, u);
}
static __device__ __forceinline__ int qperm(int k) {
  return ((k >> 3) & 3) | ((k & 7) << 2) | (k & 0x60);
}

// in_proj (all blocks) + edge bucket-scatter (0..499) + Bp build (500..759) + agg zero (760..884)
__global__ __launch_bounds__(128) void front_k(
    const float* __restrict__ x, const float* __restrict__ inW,
    const float* __restrict__ inb, const int* __restrict__ ei,
    const float* __restrict__ ea,
    const float* __restrict__ W2, const float* __restrict__ b2,
    const float* __restrict__ rW,
    unsigned short* __restrict__ hb,
    float* __restrict__ deg, int* __restrict__ cnt,
    unsigned short* __restrict__ Bp, float* __restrict__ agg,
    float* __restrict__ ea_s, int* __restrict__ dst_s) {
  int blk = blockIdx.x;
  int t = threadIdx.x;
  __shared__ float sx[INF];
  if (t < INF) sx[t] = x[blk * INF + t];
  __syncthreads();
  float acc = inb[t];
#pragma unroll
  for (int i = 0; i < INF; ++i) acc = fmaf(sx[i], inW[i * HH + t], acc);
  hb[(size_t)blk * HH + t] = f2bf(acc);

  if (blk < 500) {
    int e = blk * 128 + t;
    int src = ei[e], dst = ei[NE + e];
    atomicAdd(&deg[dst], 1.0f);
    int slot = atomicAdd(&cnt[src], 1);
    int p = src * CAP + slot;
    *(float4*)&ea_s[(size_t)p * 4] = *(const float4*)&ea[(size_t)e * 4];
    dst_s[p] = dst;
  } else if (blk < 756) {
    int r = blk - 500;            // 0..255
    int l = r >> 7, k = r & 127;
    const float* w2row = W2 + (size_t)l * (HH * HH * MM) + (size_t)k * 2048;
    float4 v0 = *(const float4*)&w2row[t * 16 + 0];
    float4 v1 = *(const float4*)&w2row[t * 16 + 4];
    float4 v2 = *(const float4*)&w2row[t * 16 + 8];
    float4 v3 = *(const float4*)&w2row[t * 16 + 12];
    unsigned short* bpr = Bp + ((size_t)l * BPR + (size_t)k * 16) * HH + t;
#pragma unroll
    for (int j = 0; j < 4; ++j) bpr[(0 + j) * HH] = f2bf((&v0.x)[j]);
#pragma unroll
    for (int j = 0; j < 4; ++j) bpr[(4 + j) * HH] = f2bf((&v1.x)[j]);
#pragma unroll
    for (int j = 0; j < 4; ++j) bpr[(8 + j) * HH] = f2bf((&v2.x)[j]);
#pragma unroll
    for (int j = 0; j < 4; ++j) bpr[(12 + j) * HH] = f2bf((&v3.x)[j]);
  } else if (blk < 760) {
    int isroot = (blk >= 758);
    int l = (blk - 756) & 1;
    const float* src = isroot ? (rW + (size_t)l * HH * MM) : (b2 + (size_t)l * 2048);
    float4 v0 = *(const float4*)&src[t * 16 + 0];
    float4 v1 = *(const float4*)&src[t * 16 + 4];
    float4 v2 = *(const float4*)&src[t * 16 + 8];
    float4 v3 = *(const float4*)&src[t * 16 + 12];
    unsigned short* bpr = Bp + ((size_t)l * BPR + 2048 + isroot * 16) * HH + t;
#pragma unroll
    for (int j = 0; j < 4; ++j) bpr[(0 + j) * HH] = f2bf((&v0.x)[j]);
#pragma unroll
    for (int j = 0; j < 4; ++j) bpr[(4 + j) * HH] = f2bf((&v1.x)[j]);
#pragma unroll
    for (int j = 0; j < 4; ++j) bpr[(8 + j) * HH] = f2bf((&v2.x)[j]);
#pragma unroll
    for (int j = 0; j < 4; ++j) bpr[(12 + j) * HH] = f2bf((&v3.x)[j]);
  } else if (blk < 885) {
    int i = (blk - 760) * 256 + t;
    uint4 z = make_uint4(0, 0, 0, 0);
    ((uint4*)agg)[i] = z;
    ((uint4*)agg)[i + 128] = z;
  }
}

// Fused layer, 32 src nodes per block (two 16-node groups sharing every B-fragment
// load -> Bp traffic halved vs 16-node version).
// Phase 1: Qn tiles for both groups = A@Bp^T -> LDS; wave7 -> B2 (both groups, LDS),
//          wave6 -> Xroot (both groups, global).
// Phase 2: per-node edge contraction P = relu1 @ Qn_tile[node], atomics into agg.
__global__ __launch_bounds__(512) void fused_layer_k(
    const unsigned short* __restrict__ hb, const float* __restrict__ hpre,
    const float* __restrict__ bnsums, const float* __restrict__ gamma,
    const float* __restrict__ beta, int bn_mode,
    const unsigned short* __restrict__ Bp,
    const float* __restrict__ ea_s, const int* __restrict__ dst_s,
    const int* __restrict__ cnt, const float* __restrict__ W1,
    const float* __restrict__ b1, float* __restrict__ agg,
    float* __restrict__ Xroot) {
  __shared__ unsigned short sA[2 * 16 * 136];
  __shared__ unsigned short sQ[2 * 16 * QS];
  __shared__ float sW1[EDF * HH];
  __shared__ float sb1[HH];
  __shared__ float sB2[32][17];
  __shared__ float sscl[HH], sshf[HH];

  int tid = threadIdx.x;
  int n0 = blockIdx.x * 32;
  int wid = tid >> 6, lane = tid & 63;
  int l15 = lane & 15, l4 = lane >> 4;

  for (int i = tid; i < EDF * HH; i += 512) sW1[i] = W1[i];
  if (tid < HH) sb1[tid] = b1[tid];
  if (bn_mode && tid < HH) {
    float mu = bnsums[tid] * (1.0f / NN);
    float var = bnsums[HH + tid] * (1.0f / NN) - mu * mu;
    float sc = gamma[tid] * rsqrtf(var + BN_EPS);
    sscl[tid] = sc;
    sshf[tid] = beta[tid] - mu * sc;
  }
  __syncthreads();

  // stage both A tiles: thread t -> group t>>8, node (t>>4)&15, 8 halfs at (t&15)*8
  {
    int g = tid >> 8;
    int node = (tid >> 4) & 15;
    int c0 = (tid & 15) * 8;
    int ng = n0 + g * 16 + node;
    if (bn_mode == 0) {
      uint4 v = *(const uint4*)&hb[(size_t)ng * HH + c0];
      *(uint4*)&sA[g * 2176 + node * 136 + c0] = v;
    } else {
      float4 v0 = *(const float4*)&hpre[(size_t)ng * HH + c0];
      float4 v1 = *(const float4*)&hpre[(size_t)ng * HH + c0 + 4];
      short8 o;
#pragma unroll
      for (int j = 0; j < 4; ++j) {
        o[j] = (short)f2bf(fmaxf(0.f, fmaf((&v0.x)[j], sscl[c0 + j], sshf[c0 + j])));
        o[4 + j] = (short)f2bf(fmaxf(0.f, fmaf((&v1.x)[j], sscl[c0 + 4 + j], sshf[c0 + 4 + j])));
      }
      *(short8*)&sA[g * 2176 + node * 136 + c0] = o;
    }
  }
  __syncthreads();

  short8 A0 = *(const short8*)&sA[l15 * 136 + 0 * 32 + l4 * 8];
  short8 A1 = *(const short8*)&sA[l15 * 136 + 1 * 32 + l4 * 8];
  short8 A2 = *(const short8*)&sA[l15 * 136 + 2 * 32 + l4 * 8];
  short8 A3 = *(const short8*)&sA[l15 * 136 + 3 * 32 + l4 * 8];
  short8 A4 = *(const short8*)&sA[2176 + l15 * 136 + 0 * 32 + l4 * 8];
  short8 A5 = *(const short8*)&sA[2176 + l15 * 136 + 1 * 32 + l4 * 8];
  short8 A6 = *(const short8*)&sA[2176 + l15 * 136 + 2 * 32 + l4 * 8];
  short8 A7 = *(const short8*)&sA[2176 + l15 * 136 + 3 * 32 + l4 * 8];

  // ---- GEMM phase: wave handles ctiles [wid*16, wid*16+16); each B-frag feeds 2 groups
  int ctb = wid * 16;
  for (int ct = ctb; ct < ctb + 16; ++ct) {
    const unsigned short* p_ = Bp + ((size_t)(ct * 16 + l15)) * HH + l4 * 8;
    short8 b0 = *(const short8*)(p_);
    short8 b1v = *(const short8*)(p_ + 32);
    short8 b2v_ = *(const short8*)(p_ + 64);
    short8 b3 = *(const short8*)(p_ + 96);
    f32x4 pa = {0.f, 0.f, 0.f, 0.f};
    f32x4 qa = {0.f, 0.f, 0.f, 0.f};
    pa = __builtin_amdgcn_mfma_f32_16x16x32_bf16(A0, b0, pa, 0, 0, 0);
    pa = __builtin_amdgcn_mfma_f32_16x16x32_bf16(A1, b1v, pa, 0, 0, 0);
    pa = __builtin_amdgcn_mfma_f32_16x16x32_bf16(A2, b2v_, pa, 0, 0, 0);
    pa = __builtin_amdgcn_mfma_f32_16x16x32_bf16(A3, b3, pa, 0, 0, 0);
    qa = __builtin_amdgcn_mfma_f32_16x16x32_bf16(A4, b0, qa, 0, 0, 0);
    qa = __builtin_amdgcn_mfma_f32_16x16x32_bf16(A5, b1v, qa, 0, 0, 0);
    qa = __builtin_amdgcn_mfma_f32_16x16x32_bf16(A6, b2v_, qa, 0, 0, 0);
    qa = __builtin_amdgcn_mfma_f32_16x16x32_bf16(A7, b3, qa, 0, 0, 0);
    int kq = qperm(ct) * 16 + l15;
#pragma unroll
    for (int j = 0; j < 4; ++j) {
      sQ[(l4 * 4 + j) * QS + kq] = f2bf(pa[j]);
      sQ[16 * QS + (l4 * 4 + j) * QS + kq] = f2bf(qa[j]);
    }
  }

  // extra ctiles: wave 7 -> B2 (rows 2048..2063, both groups -> LDS);
  //               wave 6 -> Xroot (rows 2064..2079, both groups -> global)
  if (wid >= 6) {
    int base = (wid == 7) ? 2048 : 2064;
    const unsigned short* p = Bp + ((size_t)(base + l15)) * HH + l4 * 8;
    short8 c0 = *(const short8*)(p);
    short8 c1 = *(const short8*)(p + 32);
    short8 c2 = *(const short8*)(p + 64);
    short8 c3 = *(const short8*)(p + 96);
    f32x4 pa = {0.f, 0.f, 0.f, 0.f};
    f32x4 qa = {0.f, 0.f, 0.f, 0.f};
    pa = __builtin_amdgcn_mfma_f32_16x16x32_bf16(A0, c0, pa, 0, 0, 0);
    pa = __builtin_amdgcn_mfma_f32_16x16x32_bf16(A1, c1, pa, 0, 0, 0);
    pa = __builtin_amdgcn_mfma_f32_16x16x32_bf16(A2, c2, pa, 0, 0, 0);
    pa = __builtin_amdgcn_mfma_f32_16x16x32_bf16(A3, c3, pa, 0, 0, 0);
    qa = __builtin_amdgcn_mfma_f32_16x16x32_bf16(A4, c0, qa, 0, 0, 0);
    qa = __builtin_amdgcn_mfma_f32_16x16x32_bf16(A5, c1, qa, 0, 0, 0);
    qa = __builtin_amdgcn_mfma_f32_16x16x32_bf16(A6, c2, qa, 0, 0, 0);
    qa = __builtin_amdgcn_mfma_f32_16x16x32_bf16(A7, c3, qa, 0, 0, 0);
    if (wid == 7) {
#pragma unroll
      for (int j = 0; j < 4; ++j) {
        sB2[l4 * 4 + j][l15] = pa[j];
        sB2[16 + l4 * 4 + j][l15] = qa[j];
      }
    } else {
#pragma unroll
      for (int j = 0; j < 4; ++j) {
        Xroot[(size_t)(n0 + l4 * 4 + j) * MM + l15] = pa[j];
        Xroot[(size_t)(n0 + 16 + l4 * 4 + j) * MM + l15] = qa[j];
      }
    }
  }
  __syncthreads();

  // ---- Contract phase: wave handles 4 nodes (2 in each group) ----
  for (int gi = 0; gi < 2; ++gi) {
    for (int ni = 0; ni < 2; ++ni) {
      int nl = gi * 16 + wid * 2 + ni;
      int n = n0 + nl;
      int count = cnt[n];
      if (count == 0) continue;

      const unsigned short* sq = &sQ[gi * 16 * QS + (nl & 15) * QS];
      short8 qb0, qb1, qb2, qb3;
#pragma unroll
      for (int j = 0; j < 8; ++j) {
        qb0[j] = (short)sq[qperm(0 * 32 + l4 * 8 + j) * 16 + l15];
        qb1[j] = (short)sq[qperm(1 * 32 + l4 * 8 + j) * 16 + l15];
        qb2[j] = (short)sq[qperm(2 * 32 + l4 * 8 + j) * 16 + l15];
        qb3[j] = (short)sq[qperm(3 * 32 + l4 * 8 + j) * 16 + l15];
      }
      float b2v = sB2[nl][l15];

      const float* eab = ea_s + (size_t)n * CAP * 4;
      const int* dsb = dst_s + (size_t)n * CAP;
      for (int t0 = 0; t0 < count; t0 += 16) {
        int rr = t0 + l15;
        bool valid = rr < count;
        float4 eav = valid ? *(const float4*)&eab[(size_t)rr * 4]
                           : make_float4(0.f, 0.f, 0.f, 0.f);
        f32x4 acc = {0.f, 0.f, 0.f, 0.f};
#pragma unroll
        for (int ks = 0; ks < 4; ++ks) {
          short8 a;
#pragma unroll
          for (int j = 0; j < 8; ++j) {
            int k = ks * 32 + l4 * 8 + j;
            float r = fmaf(eav.w, sW1[3 * HH + k],
                       fmaf(eav.z, sW1[2 * HH + k],
                         fmaf(eav.y, sW1[HH + k], fmaf(eav.x, sW1[k], sb1[k]))));
            a[j] = valid ? (short)f2bf(fmaxf(r, 0.f)) : (short)0;
          }
          short8 qb = (ks == 0) ? qb0 : (ks == 1) ? qb1 : (ks == 2) ? qb2 : qb3;
          acc = __builtin_amdgcn_mfma_f32_16x16x32_bf16(a, qb, acc, 0, 0, 0);
        }
#pragma unroll
        for (int j = 0; j < 4; ++j) {
          int r = t0 + l4 * 4 + j;
          if (r < count) {
            atomicAdd(&agg[(size_t)dsb[r] * MM + l15], acc[j] + b2v);
          }
        }
      }
    }
  }
}

// 16 nodes/block: xm = agg/deg + Xroot + cbias ; hp = resid + xm@msgW + msgb
// fused BN partial sums; zeroes its agg slice for next layer.
__global__ __launch_bounds__(256) void node_update_k(
    const unsigned short* __restrict__ hb, const float* __restrict__ hsrc_pre,
    const float* __restrict__ bnsums, const float* __restrict__ gamma,
    const float* __restrict__ beta, int bn_mode,
    float* __restrict__ agg, const float* __restrict__ deg,
    const float* __restrict__ Xroot, const float* __restrict__ cbias,
    const float* __restrict__ msgW, const float* __restrict__ msgb,
    float* __restrict__ hpre, float* __restrict__ sums) {
  __shared__ float smw[MM * HH];
  __shared__ float xm[16][MM];
  __shared__ float scb[MM];
  __shared__ float smb[HH];
  __shared__ float red[256];
  __shared__ float sscl[HH], sshf[HH];
  int tid = threadIdx.x;
  int n0 = blockIdx.x * 16;
  for (int i = tid; i < MM * HH; i += 256) smw[i] = msgW[i];
  if (tid < MM) scb[tid] = cbias[tid];
  if (tid < HH) smb[tid] = msgb[tid];
  if (bn_mode && tid < HH) {
    float mu = bnsums[tid] * (1.0f / NN);
    float var = bnsums[HH + tid] * (1.0f / NN) - mu * mu;
    float sc = gamma[tid] * rsqrtf(var + BN_EPS);
    sscl[tid] = sc;
    sshf[tid] = beta[tid] - mu * sc;
  }
  __syncthreads();

  {
    int ni = tid >> 4, m = tid & 15;
    int n = n0 + ni;
    size_t idx = (size_t)n * MM + m;
    xm[ni][m] = agg[idx] / fmaxf(deg[n], 1.0f) + Xroot[idx] + scb[m];
  }
  __syncthreads();
  agg[(size_t)n0 * MM + tid] = 0.f;

  int t = tid & 127;
  float lsum = 0.f, lss = 0.f;
#pragma unroll
  for (int pass = 0; pass < 8; ++pass) {
    int ni = pass * 2 + (tid >> 7);
    size_t idx = (size_t)(n0 + ni) * HH + t;
    float resid;
    if (bn_mode) {
      resid = fmaxf(0.f, fmaf(hsrc_pre[idx], sscl[t], sshf[t]));
    } else {
      resid = bf2f(hb[idx]);
    }
    float hp = resid + smb[t];
#pragma unroll
    for (int m = 0; m < MM; ++m) hp = fmaf(xm[ni][m], smw[m * HH + t], hp);
    hpre[idx] = hp;
    lsum += hp;
    lss = fmaf(hp, hp, lss);
  }
  red[tid] = lsum;
  __syncthreads();
  if (tid < 128) atomicAdd(&sums[t], red[tid] + red[tid + 128]);
  __syncthreads();
  red[tid] = lss;
  __syncthreads();
  if (tid < 128) atomicAdd(&sums[HH + t], red[tid] + red[tid + 128]);
}

__global__ void out_proj_k(const float* __restrict__ hpre,
                           const float* __restrict__ bnsums,
                           const float* __restrict__ gamma,
                           const float* __restrict__ beta,
                           const float* __restrict__ W, const float* __restrict__ b,
                           float* __restrict__ out) {
  __shared__ float sscl[HH], sshf[HH];
  int tid = threadIdx.x;
  if (tid < HH) {
    float mu = bnsums[tid] * (1.0f / NN);
    float var = bnsums[HH + tid] * (1.0f / NN) - mu * mu;
    float sc = gamma[tid] * rsqrtf(var + BN_EPS);
    sscl[tid] = sc;
    sshf[tid] = beta[tid] - mu * sc;
  }
  __syncthreads();
  int n = blockIdx.x * 4 + (tid >> 6);
  int lane = tid & 63;
  if (n >= NN) return;
  float acc0 = 0.f, acc1 = 0.f, acc2 = 0.f, acc3 = 0.f;
#pragma unroll
  for (int rep = 0; rep < 2; ++rep) {
    int hh = lane + rep * 64;
    float hv = fmaxf(0.f, fmaf(hpre[(size_t)n * HH + hh], sscl[hh], sshf[hh]));
    acc0 = fmaf(hv, W[hh * OUTF + 0], acc0);
    acc1 = fmaf(hv, W[hh * OUTF + 1], acc1);
    acc2 = fmaf(hv, W[hh * OUTF + 2], acc2);
    acc3 = fmaf(hv, W[hh * OUTF + 3], acc3);
  }
#pragma unroll
  for (int s = 32; s > 0; s >>= 1) {
    acc0 += __shfl_down(acc0, s);
    acc1 += __shfl_down(acc1, s);
    acc2 += __shfl_down(acc2, s);
    acc3 += __shfl_down(acc3, s);
  }
  if (lane == 0) {
    out[n * OUTF + 0] = acc0 + b[0];
    out[n * OUTF + 1] = acc1 + b[1];
    out[n * OUTF + 2] = acc2 + b[2];
    out[n * OUTF + 3] = acc3 + b[3];
  }
}

extern "C" void kernel_launch(void* const* d_in, const int* in_sizes, int n_in,
                              void* d_out, int out_size, void* d_ws, size_t ws_size,
                              hipStream_t stream) {
  (void)in_sizes; (void)n_in; (void)out_size; (void)ws_size;
  const float* x    = (const float*)d_in[0];
  const int* ei     = (const int*)d_in[1];
  const float* ea   = (const float*)d_in[2];
  const float* inW  = (const float*)d_in[3];
  const float* inb  = (const float*)d_in[4];
  const float* cW1  = (const float*)d_in[5];
  const float* cb1  = (const float*)d_in[6];
  const float* cW2  = (const float*)d_in[7];
  const float* cb2  = (const float*)d_in[8];
  const float* rW   = (const float*)d_in[9];
  const float* cbias= (const float*)d_in[10];
  const float* gam  = (const float*)d_in[11];
  const float* bet  = (const float*)d_in[12];
  const float* mW   = (const float*)d_in[13];
  const float* mb   = (const float*)d_in[14];
  const float* oW   = (const float*)d_in[15];
  const float* ob   = (const float*)d_in[16];
  float* out = (float*)d_out;

  float* ws = (float*)d_ws;
  size_t off = 0;
  // contiguous zero region: deg, cnt, sums0, sums1 (one small memset)
  float* deg   = ws + off; off += 8192;
  int* cnt     = (int*)(ws + off); off += 8192;
  float* sums0 = ws + off; off += 256;
  float* sums1 = ws + off; off += 256;
  size_t zero_floats = off;
  float* agg   = ws + off; off += (size_t)NN * MM;      // zeroed by front_k
  float* hpre0 = ws + off; off += (size_t)NN * HH;
  float* hpre1 = ws + off; off += (size_t)NN * HH;
  float* Xroot = ws + off; off += (size_t)NN * MM;
  unsigned short* hb = (unsigned short*)(ws + off); off += (size_t)NN * HH / 2;
  unsigned short* Bp = (unsigned short*)(ws + off); off += (size_t)NL * BPR * HH / 2;
  float* ea_s  = ws + off; off += (size_t)NN * CAP * 4;
  int* dst_s   = (int*)(ws + off); off += (size_t)NN * CAP;

  hipMemsetAsync(deg, 0, zero_floats * sizeof(float), stream);
  front_k<<<NN, 128, 0, stream>>>(x, inW, inb, ei, ea, cW2, cb2, rW, hb,
                                  deg, cnt, Bp, agg, ea_s, dst_s);

  // ---- layer 0 ----
  fused_layer_k<<<NN / 32, 512, 0, stream>>>(hb, hpre0, sums0, gam, bet, 0,
                                             Bp, ea_s, dst_s, cnt, cW1, cb1,
                                             agg, Xroot);
  node_update_k<<<NN / 16, 256, 0, stream>>>(hb, hpre0, sums0, gam, bet, 0,
                                             agg, deg, Xroot, cbias, mW, mb,
                                             hpre0, sums0);
  // ---- layer 1 ----
  fused_layer_k<<<NN / 32, 512, 0, stream>>>(hb, hpre0, sums0, gam, bet, 1,
                                             Bp + (size_t)BPR * HH, ea_s, dst_s,
                                             cnt, cW1 + EDF * HH, cb1 + HH,
                                             agg, Xroot);
  node_update_k<<<NN / 16, 256, 0, stream>>>(hb, hpre0, sums0, gam, bet, 1,
                                             agg, deg, Xroot, cbias + MM,
                                             mW + MM * HH, mb + HH,
                                             hpre1, sums1);
  out_proj_k<<<NN / 4, 256, 0, stream>>>(hpre1, sums1, gam + HH, bet + HH,
                                         oW, ob, out);
}

// Round 16
// 120.981 us; speedup vs baseline: 1.2543x; 1.1047x over previous
//
#include <hip/hip_runtime.h>

#define NN 8000
#define NE 64000
#define INF 16
#define HH 128
#define MM 16
#define EDF 4
#define OUTF 4
#define NL 2
#define BN_EPS 1e-5f
#define BPR 2080          // Bp rows per layer: 2048 qn + 16 b2 + 16 rootW
#define CAP 48            // per-node edge bucket capacity
#define QS 2052           // sQ node stride in halfs

typedef __attribute__((ext_vector_type(8))) short short8;
typedef __attribute__((ext_vector_type(4))) float f32x4;

static __device__ __forceinline__ unsigned short f2bf(float f) {
  unsigned u = __builtin_bit_cast(unsigned, f);
  u = (u + 0x7fffu + ((u >> 16) & 1u)) >> 16;
  return (unsigned short)u;
}
static __device__ __forceinline__ float bf2f(unsigned short s) {
  unsigned u = ((unsigned)s) << 16;
  return __builtin_bit_cast(float, u);
}
static __device__ __forceinline__ int qperm(int k) {
  return ((k >> 3) & 3) | ((k & 7) << 2) | (k & 0x60);
}

// in_proj (all blocks) + edge bucket-scatter (0..499) + Bp build (500..759) + agg zero (760..884)
__global__ __launch_bounds__(128) void front_k(
    const float* __restrict__ x, const float* __restrict__ inW,
    const float* __restrict__ inb, const int* __restrict__ ei,
    const float* __restrict__ ea,
    const float* __restrict__ W2, const float* __restrict__ b2,
    const float* __restrict__ rW,
    unsigned short* __restrict__ hb,
    float* __restrict__ deg, int* __restrict__ cnt,
    unsigned short* __restrict__ Bp, float* __restrict__ agg,
    float* __restrict__ ea_s, int* __restrict__ dst_s) {
  int blk = blockIdx.x;
  int t = threadIdx.x;
  __shared__ float sx[INF];
  if (t < INF) sx[t] = x[blk * INF + t];
  __syncthreads();
  float acc = inb[t];
#pragma unroll
  for (int i = 0; i < INF; ++i) acc = fmaf(sx[i], inW[i * HH + t], acc);
  hb[(size_t)blk * HH + t] = f2bf(acc);

  if (blk < 500) {
    int e = blk * 128 + t;
    int src = ei[e], dst = ei[NE + e];
    atomicAdd(&deg[dst], 1.0f);
    int slot = atomicAdd(&cnt[src], 1);
    int p = src * CAP + slot;
    *(float4*)&ea_s[(size_t)p * 4] = *(const float4*)&ea[(size_t)e * 4];
    dst_s[p] = dst;
  } else if (blk < 756) {
    int r = blk - 500;            // 0..255
    int l = r >> 7, k = r & 127;
    const float* w2row = W2 + (size_t)l * (HH * HH * MM) + (size_t)k * 2048;
    float4 v0 = *(const float4*)&w2row[t * 16 + 0];
    float4 v1 = *(const float4*)&w2row[t * 16 + 4];
    float4 v2 = *(const float4*)&w2row[t * 16 + 8];
    float4 v3 = *(const float4*)&w2row[t * 16 + 12];
    unsigned short* bpr = Bp + ((size_t)l * BPR + (size_t)k * 16) * HH + t;
#pragma unroll
    for (int j = 0; j < 4; ++j) bpr[(0 + j) * HH] = f2bf((&v0.x)[j]);
#pragma unroll
    for (int j = 0; j < 4; ++j) bpr[(4 + j) * HH] = f2bf((&v1.x)[j]);
#pragma unroll
    for (int j = 0; j < 4; ++j) bpr[(8 + j) * HH] = f2bf((&v2.x)[j]);
#pragma unroll
    for (int j = 0; j < 4; ++j) bpr[(12 + j) * HH] = f2bf((&v3.x)[j]);
  } else if (blk < 760) {
    int isroot = (blk >= 758);
    int l = (blk - 756) & 1;
    const float* src = isroot ? (rW + (size_t)l * HH * MM) : (b2 + (size_t)l * 2048);
    float4 v0 = *(const float4*)&src[t * 16 + 0];
    float4 v1 = *(const float4*)&src[t * 16 + 4];
    float4 v2 = *(const float4*)&src[t * 16 + 8];
    float4 v3 = *(const float4*)&src[t * 16 + 12];
    unsigned short* bpr = Bp + ((size_t)l * BPR + 2048 + isroot * 16) * HH + t;
#pragma unroll
    for (int j = 0; j < 4; ++j) bpr[(0 + j) * HH] = f2bf((&v0.x)[j]);
#pragma unroll
    for (int j = 0; j < 4; ++j) bpr[(4 + j) * HH] = f2bf((&v1.x)[j]);
#pragma unroll
    for (int j = 0; j < 4; ++j) bpr[(8 + j) * HH] = f2bf((&v2.x)[j]);
#pragma unroll
    for (int j = 0; j < 4; ++j) bpr[(12 + j) * HH] = f2bf((&v3.x)[j]);
  } else if (blk < 885) {
    int i = (blk - 760) * 256 + t;
    uint4 z = make_uint4(0, 0, 0, 0);
    ((uint4*)agg)[i] = z;
    ((uint4*)agg)[i + 128] = z;
  }
}

// Fused layer, 32 src nodes per block, 1024 threads (16 waves, 4 waves/SIMD at
// 1 block/CU) — same Bp traffic as the 512-thread version, double latency hiding.
// Phase 1: Qn tiles (both groups) = A@Bp^T -> LDS; wave14 -> B2 (LDS),
//          wave15 -> Xroot (global).
// Phase 2: per-node edge contraction P = relu1 @ Qn_tile[node], atomics into agg.
__global__ __launch_bounds__(1024) void fused_layer_k(
    const unsigned short* __restrict__ hb, const float* __restrict__ hpre,
    const float* __restrict__ bnsums, const float* __restrict__ gamma,
    const float* __restrict__ beta, int bn_mode,
    const unsigned short* __restrict__ Bp,
    const float* __restrict__ ea_s, const int* __restrict__ dst_s,
    const int* __restrict__ cnt, const float* __restrict__ W1,
    const float* __restrict__ b1, float* __restrict__ agg,
    float* __restrict__ Xroot) {
  __shared__ unsigned short sA[2 * 16 * 136];
  __shared__ unsigned short sQ[2 * 16 * QS];
  __shared__ float sW1[EDF * HH];
  __shared__ float sb1[HH];
  __shared__ float sB2[32][17];
  __shared__ float sscl[HH], sshf[HH];

  int tid = threadIdx.x;
  int n0 = blockIdx.x * 32;
  int wid = tid >> 6, lane = tid & 63;
  int l15 = lane & 15, l4 = lane >> 4;

  for (int i = tid; i < EDF * HH; i += 1024) sW1[i] = W1[i];
  if (tid < HH) sb1[tid] = b1[tid];
  if (bn_mode && tid >= 128 && tid < 256) {
    int c = tid - 128;
    float mu = bnsums[c] * (1.0f / NN);
    float var = bnsums[HH + c] * (1.0f / NN) - mu * mu;
    float sc = gamma[c] * rsqrtf(var + BN_EPS);
    sscl[c] = sc;
    sshf[c] = beta[c] - mu * sc;
  }
  __syncthreads();

  // stage both A tiles (threads 0..511): group tid>>8, node (tid>>4)&15, cols (tid&15)*8
  if (tid < 512) {
    int g = tid >> 8;
    int node = (tid >> 4) & 15;
    int c0 = (tid & 15) * 8;
    int ng = n0 + g * 16 + node;
    if (bn_mode == 0) {
      uint4 v = *(const uint4*)&hb[(size_t)ng * HH + c0];
      *(uint4*)&sA[g * 2176 + node * 136 + c0] = v;
    } else {
      float4 v0 = *(const float4*)&hpre[(size_t)ng * HH + c0];
      float4 v1 = *(const float4*)&hpre[(size_t)ng * HH + c0 + 4];
      short8 o;
#pragma unroll
      for (int j = 0; j < 4; ++j) {
        o[j] = (short)f2bf(fmaxf(0.f, fmaf((&v0.x)[j], sscl[c0 + j], sshf[c0 + j])));
        o[4 + j] = (short)f2bf(fmaxf(0.f, fmaf((&v1.x)[j], sscl[c0 + 4 + j], sshf[c0 + 4 + j])));
      }
      *(short8*)&sA[g * 2176 + node * 136 + c0] = o;
    }
  }
  __syncthreads();

  short8 A0 = *(const short8*)&sA[l15 * 136 + 0 * 32 + l4 * 8];
  short8 A1 = *(const short8*)&sA[l15 * 136 + 1 * 32 + l4 * 8];
  short8 A2 = *(const short8*)&sA[l15 * 136 + 2 * 32 + l4 * 8];
  short8 A3 = *(const short8*)&sA[l15 * 136 + 3 * 32 + l4 * 8];
  short8 A4 = *(const short8*)&sA[2176 + l15 * 136 + 0 * 32 + l4 * 8];
  short8 A5 = *(const short8*)&sA[2176 + l15 * 136 + 1 * 32 + l4 * 8];
  short8 A6 = *(const short8*)&sA[2176 + l15 * 136 + 2 * 32 + l4 * 8];
  short8 A7 = *(const short8*)&sA[2176 + l15 * 136 + 3 * 32 + l4 * 8];

  // ---- GEMM phase: wave handles ctiles [wid*8, wid*8+8); each B-frag feeds 2 groups
  int ctb = wid * 8;
  for (int ct = ctb; ct < ctb + 8; ++ct) {
    const unsigned short* p_ = Bp + ((size_t)(ct * 16 + l15)) * HH + l4 * 8;
    short8 b0 = *(const short8*)(p_);
    short8 b1v = *(const short8*)(p_ + 32);
    short8 b2v_ = *(const short8*)(p_ + 64);
    short8 b3 = *(const short8*)(p_ + 96);
    f32x4 pa = {0.f, 0.f, 0.f, 0.f};
    f32x4 qa = {0.f, 0.f, 0.f, 0.f};
    pa = __builtin_amdgcn_mfma_f32_16x16x32_bf16(A0, b0, pa, 0, 0, 0);
    pa = __builtin_amdgcn_mfma_f32_16x16x32_bf16(A1, b1v, pa, 0, 0, 0);
    pa = __builtin_amdgcn_mfma_f32_16x16x32_bf16(A2, b2v_, pa, 0, 0, 0);
    pa = __builtin_amdgcn_mfma_f32_16x16x32_bf16(A3, b3, pa, 0, 0, 0);
    qa = __builtin_amdgcn_mfma_f32_16x16x32_bf16(A4, b0, qa, 0, 0, 0);
    qa = __builtin_amdgcn_mfma_f32_16x16x32_bf16(A5, b1v, qa, 0, 0, 0);
    qa = __builtin_amdgcn_mfma_f32_16x16x32_bf16(A6, b2v_, qa, 0, 0, 0);
    qa = __builtin_amdgcn_mfma_f32_16x16x32_bf16(A7, b3, qa, 0, 0, 0);
    int kq = qperm(ct) * 16 + l15;
#pragma unroll
    for (int j = 0; j < 4; ++j) {
      sQ[(l4 * 4 + j) * QS + kq] = f2bf(pa[j]);
      sQ[16 * QS + (l4 * 4 + j) * QS + kq] = f2bf(qa[j]);
    }
  }

  // extra ctiles: wave 14 -> B2 (rows 2048..2063, both groups -> LDS);
  //               wave 15 -> Xroot (rows 2064..2079, both groups -> global)
  if (wid >= 14) {
    int base = (wid == 14) ? 2048 : 2064;
    const unsigned short* p = Bp + ((size_t)(base + l15)) * HH + l4 * 8;
    short8 c0 = *(const short8*)(p);
    short8 c1 = *(const short8*)(p + 32);
    short8 c2 = *(const short8*)(p + 64);
    short8 c3 = *(const short8*)(p + 96);
    f32x4 pa = {0.f, 0.f, 0.f, 0.f};
    f32x4 qa = {0.f, 0.f, 0.f, 0.f};
    pa = __builtin_amdgcn_mfma_f32_16x16x32_bf16(A0, c0, pa, 0, 0, 0);
    pa = __builtin_amdgcn_mfma_f32_16x16x32_bf16(A1, c1, pa, 0, 0, 0);
    pa = __builtin_amdgcn_mfma_f32_16x16x32_bf16(A2, c2, pa, 0, 0, 0);
    pa = __builtin_amdgcn_mfma_f32_16x16x32_bf16(A3, c3, pa, 0, 0, 0);
    qa = __builtin_amdgcn_mfma_f32_16x16x32_bf16(A4, c0, qa, 0, 0, 0);
    qa = __builtin_amdgcn_mfma_f32_16x16x32_bf16(A5, c1, qa, 0, 0, 0);
    qa = __builtin_amdgcn_mfma_f32_16x16x32_bf16(A6, c2, qa, 0, 0, 0);
    qa = __builtin_amdgcn_mfma_f32_16x16x32_bf16(A7, c3, qa, 0, 0, 0);
    if (wid == 14) {
#pragma unroll
      for (int j = 0; j < 4; ++j) {
        sB2[l4 * 4 + j][l15] = pa[j];
        sB2[16 + l4 * 4 + j][l15] = qa[j];
      }
    } else {
#pragma unroll
      for (int j = 0; j < 4; ++j) {
        Xroot[(size_t)(n0 + l4 * 4 + j) * MM + l15] = pa[j];
        Xroot[(size_t)(n0 + 16 + l4 * 4 + j) * MM + l15] = qa[j];
      }
    }
  }
  __syncthreads();

  // ---- Contract phase: wave handles 2 nodes (1 in each group) ----
  for (int gi = 0; gi < 2; ++gi) {
    int nl = gi * 16 + wid;
    int n = n0 + nl;
    int count = cnt[n];
    if (count == 0) continue;

    const unsigned short* sq = &sQ[gi * 16 * QS + (nl & 15) * QS];
    short8 qb0, qb1, qb2, qb3;
#pragma unroll
    for (int j = 0; j < 8; ++j) {
      qb0[j] = (short)sq[qperm(0 * 32 + l4 * 8 + j) * 16 + l15];
      qb1[j] = (short)sq[qperm(1 * 32 + l4 * 8 + j) * 16 + l15];
      qb2[j] = (short)sq[qperm(2 * 32 + l4 * 8 + j) * 16 + l15];
      qb3[j] = (short)sq[qperm(3 * 32 + l4 * 8 + j) * 16 + l15];
    }
    float b2v = sB2[nl][l15];

    const float* eab = ea_s + (size_t)n * CAP * 4;
    const int* dsb = dst_s + (size_t)n * CAP;
    for (int t0 = 0; t0 < count; t0 += 16) {
      int rr = t0 + l15;
      bool valid = rr < count;
      float4 eav = valid ? *(const float4*)&eab[(size_t)rr * 4]
                         : make_float4(0.f, 0.f, 0.f, 0.f);
      f32x4 acc = {0.f, 0.f, 0.f, 0.f};
#pragma unroll
      for (int ks = 0; ks < 4; ++ks) {
        short8 a;
#pragma unroll
        for (int j = 0; j < 8; ++j) {
          int k = ks * 32 + l4 * 8 + j;
          float r = fmaf(eav.w, sW1[3 * HH + k],
                     fmaf(eav.z, sW1[2 * HH + k],
                       fmaf(eav.y, sW1[HH + k], fmaf(eav.x, sW1[k], sb1[k]))));
          a[j] = valid ? (short)f2bf(fmaxf(r, 0.f)) : (short)0;
        }
        short8 qb = (ks == 0) ? qb0 : (ks == 1) ? qb1 : (ks == 2) ? qb2 : qb3;
        acc = __builtin_amdgcn_mfma_f32_16x16x32_bf16(a, qb, acc, 0, 0, 0);
      }
#pragma unroll
      for (int j = 0; j < 4; ++j) {
        int r = t0 + l4 * 4 + j;
        if (r < count) {
          atomicAdd(&agg[(size_t)dsb[r] * MM + l15], acc[j] + b2v);
        }
      }
    }
  }
}

// 16 nodes/block: xm = agg/deg + Xroot + cbias ; hp = resid + xm@msgW + msgb
// fused BN partial sums; zeroes its agg slice for next layer.
__global__ __launch_bounds__(256) void node_update_k(
    const unsigned short* __restrict__ hb, const float* __restrict__ hsrc_pre,
    const float* __restrict__ bnsums, const float* __restrict__ gamma,
    const float* __restrict__ beta, int bn_mode,
    float* __restrict__ agg, const float* __restrict__ deg,
    const float* __restrict__ Xroot, const float* __restrict__ cbias,
    const float* __restrict__ msgW, const float* __restrict__ msgb,
    float* __restrict__ hpre, float* __restrict__ sums) {
  __shared__ float smw[MM * HH];
  __shared__ float xm[16][MM];
  __shared__ float scb[MM];
  __shared__ float smb[HH];
  __shared__ float red[256];
  __shared__ float sscl[HH], sshf[HH];
  int tid = threadIdx.x;
  int n0 = blockIdx.x * 16;
  for (int i = tid; i < MM * HH; i += 256) smw[i] = msgW[i];
  if (tid < MM) scb[tid] = cbias[tid];
  if (tid < HH) smb[tid] = msgb[tid];
  if (bn_mode && tid < HH) {
    float mu = bnsums[tid] * (1.0f / NN);
    float var = bnsums[HH + tid] * (1.0f / NN) - mu * mu;
    float sc = gamma[tid] * rsqrtf(var + BN_EPS);
    sscl[tid] = sc;
    sshf[tid] = beta[tid] - mu * sc;
  }
  __syncthreads();

  {
    int ni = tid >> 4, m = tid & 15;
    int n = n0 + ni;
    size_t idx = (size_t)n * MM + m;
    xm[ni][m] = agg[idx] / fmaxf(deg[n], 1.0f) + Xroot[idx] + scb[m];
  }
  __syncthreads();
  agg[(size_t)n0 * MM + tid] = 0.f;

  int t = tid & 127;
  float lsum = 0.f, lss = 0.f;
#pragma unroll
  for (int pass = 0; pass < 8; ++pass) {
    int ni = pass * 2 + (tid >> 7);
    size_t idx = (size_t)(n0 + ni) * HH + t;
    float resid;
    if (bn_mode) {
      resid = fmaxf(0.f, fmaf(hsrc_pre[idx], sscl[t], sshf[t]));
    } else {
      resid = bf2f(hb[idx]);
    }
    float hp = resid + smb[t];
#pragma unroll
    for (int m = 0; m < MM; ++m) hp = fmaf(xm[ni][m], smw[m * HH + t], hp);
    hpre[idx] = hp;
    lsum += hp;
    lss = fmaf(hp, hp, lss);
  }
  red[tid] = lsum;
  __syncthreads();
  if (tid < 128) atomicAdd(&sums[t], red[tid] + red[tid + 128]);
  __syncthreads();
  red[tid] = lss;
  __syncthreads();
  if (tid < 128) atomicAdd(&sums[HH + t], red[tid] + red[tid + 128]);
}

__global__ void out_proj_k(const float* __restrict__ hpre,
                           const float* __restrict__ bnsums,
                           const float* __restrict__ gamma,
                           const float* __restrict__ beta,
                           const float* __restrict__ W, const float* __restrict__ b,
                           float* __restrict__ out) {
  __shared__ float sscl[HH], sshf[HH];
  int tid = threadIdx.x;
  if (tid < HH) {
    float mu = bnsums[tid] * (1.0f / NN);
    float var = bnsums[HH + tid] * (1.0f / NN) - mu * mu;
    float sc = gamma[tid] * rsqrtf(var + BN_EPS);
    sscl[tid] = sc;
    sshf[tid] = beta[tid] - mu * sc;
  }
  __syncthreads();
  int n = blockIdx.x * 4 + (tid >> 6);
  int lane = tid & 63;
  if (n >= NN) return;
  float acc0 = 0.f, acc1 = 0.f, acc2 = 0.f, acc3 = 0.f;
#pragma unroll
  for (int rep = 0; rep < 2; ++rep) {
    int hh = lane + rep * 64;
    float hv = fmaxf(0.f, fmaf(hpre[(size_t)n * HH + hh], sscl[hh], sshf[hh]));
    acc0 = fmaf(hv, W[hh * OUTF + 0], acc0);
    acc1 = fmaf(hv, W[hh * OUTF + 1], acc1);
    acc2 = fmaf(hv, W[hh * OUTF + 2], acc2);
    acc3 = fmaf(hv, W[hh * OUTF + 3], acc3);
  }
#pragma unroll
  for (int s = 32; s > 0; s >>= 1) {
    acc0 += __shfl_down(acc0, s);
    acc1 += __shfl_down(acc1, s);
    acc2 += __shfl_down(acc2, s);
    acc3 += __shfl_down(acc3, s);
  }
  if (lane == 0) {
    out[n * OUTF + 0] = acc0 + b[0];
    out[n * OUTF + 1] = acc1 + b[1];
    out[n * OUTF + 2] = acc2 + b[2];
    out[n * OUTF + 3] = acc3 + b[3];
  }
}

extern "C" void kernel_launch(void* const* d_in, const int* in_sizes, int n_in,
                              void* d_out, int out_size, void* d_ws, size_t ws_size,
                              hipStream_t stream) {
  (void)in_sizes; (void)n_in; (void)out_size; (void)ws_size;
  const float* x    = (const float*)d_in[0];
  const int* ei     = (const int*)d_in[1];
  const float* ea   = (const float*)d_in[2];
  const float* inW  = (const float*)d_in[3];
  const float* inb  = (const float*)d_in[4];
  const float* cW1  = (const float*)d_in[5];
  const float* cb1  = (const float*)d_in[6];
  const float* cW2  = (const float*)d_in[7];
  const float* cb2  = (const float*)d_in[8];
  const float* rW   = (const float*)d_in[9];
  const float* cbias= (const float*)d_in[10];
  const float* gam  = (const float*)d_in[11];
  const float* bet  = (const float*)d_in[12];
  const float* mW   = (const float*)d_in[13];
  const float* mb   = (const float*)d_in[14];
  const float* oW   = (const float*)d_in[15];
  const float* ob   = (const float*)d_in[16];
  float* out = (float*)d_out;

  float* ws = (float*)d_ws;
  size_t off = 0;
  // contiguous zero region: deg, cnt, sums0, sums1 (one small memset)
  float* deg   = ws + off; off += 8192;
  int* cnt     = (int*)(ws + off); off += 8192;
  float* sums0 = ws + off; off += 256;
  float* sums1 = ws + off; off += 256;
  size_t zero_floats = off;
  float* agg   = ws + off; off += (size_t)NN * MM;      // zeroed by front_k
  float* hpre0 = ws + off; off += (size_t)NN * HH;
  float* hpre1 = ws + off; off += (size_t)NN * HH;
  float* Xroot = ws + off; off += (size_t)NN * MM;
  unsigned short* hb = (unsigned short*)(ws + off); off += (size_t)NN * HH / 2;
  unsigned short* Bp = (unsigned short*)(ws + off); off += (size_t)NL * BPR * HH / 2;
  float* ea_s  = ws + off; off += (size_t)NN * CAP * 4;
  int* dst_s   = (int*)(ws + off); off += (size_t)NN * CAP;

  hipMemsetAsync(deg, 0, zero_floats * sizeof(float), stream);
  front_k<<<NN, 128, 0, stream>>>(x, inW, inb, ei, ea, cW2, cb2, rW, hb,
                                  deg, cnt, Bp, agg, ea_s, dst_s);

  // ---- layer 0 ----
  fused_layer_k<<<NN / 32, 1024, 0, stream>>>(hb, hpre0, sums0, gam, bet, 0,
                                              Bp, ea_s, dst_s, cnt, cW1, cb1,
                                              agg, Xroot);
  node_update_k<<<NN / 16, 256, 0, stream>>>(hb, hpre0, sums0, gam, bet, 0,
                                             agg, deg, Xroot, cbias, mW, mb,
                                             hpre0, sums0);
  // ---- layer 1 ----
  fused_layer_k<<<NN / 32, 1024, 0, stream>>>(hb, hpre0, sums0, gam, bet, 1,
                                              Bp + (size_t)BPR * HH, ea_s, dst_s,
                                              cnt, cW1 + EDF * HH, cb1 + HH,
                                              agg, Xroot);
  node_update_k<<<NN / 16, 256, 0, stream>>>(hb, hpre0, sums0, gam, bet, 1,
                                             agg, deg, Xroot, cbias + MM,
                                             mW + MM * HH, mb + HH,
                                             hpre1, sums1);
  out_proj_k<<<NN / 4, 256, 0, stream>>>(hpre1, sums1, gam + HH, bet + HH,
                                         oW, ob, out);
}

// Round 17
// 120.653 us; speedup vs baseline: 1.2577x; 1.0027x over previous
//
#include <hip/hip_runtime.h>

#define NN 8000
#define NE 64000
#define INF 16
#define HH 128
#define MM 16
#define EDF 4
#define OUTF 4
#define NL 2
#define BN_EPS 1e-5f
#define BPR 2080          // Bp rows per layer: 2048 qn + 16 b2 + 16 rootW
#define CAP 48            // per-node edge bucket capacity
#define QS 2052           // sQ node stride in halfs

typedef __attribute__((ext_vector_type(8))) short short8;
typedef __attribute__((ext_vector_type(4))) float f32x4;

static __device__ __forceinline__ unsigned short f2bf(float f) {
  unsigned u = __builtin_bit_cast(unsigned, f);
  u = (u + 0x7fffu + ((u >> 16) & 1u)) >> 16;
  return (unsigned short)u;
}
static __device__ __forceinline__ float bf2f(unsigned short s) {
  unsigned u = ((unsigned)s) << 16;
  return __builtin_bit_cast(float, u);
}
static __device__ __forceinline__ int qperm(int k) {
  return ((k >> 3) & 3) | ((k & 7) << 2) | (k & 0x60);
}

// in_proj (all blocks) + edge bucket-scatter (0..499) + Bp build (500..759) + agg zero (760..884)
__global__ __launch_bounds__(128) void front_k(
    const float* __restrict__ x, const float* __restrict__ inW,
    const float* __restrict__ inb, const int* __restrict__ ei,
    const float* __restrict__ ea,
    const float* __restrict__ W2, const float* __restrict__ b2,
    const float* __restrict__ rW,
    unsigned short* __restrict__ hb,
    float* __restrict__ deg, int* __restrict__ cnt,
    unsigned short* __restrict__ Bp, float* __restrict__ agg,
    float* __restrict__ ea_s, int* __restrict__ dst_s) {
  int blk = blockIdx.x;
  int t = threadIdx.x;
  __shared__ float sx[INF];
  if (t < INF) sx[t] = x[blk * INF + t];
  __syncthreads();
  float acc = inb[t];
#pragma unroll
  for (int i = 0; i < INF; ++i) acc = fmaf(sx[i], inW[i * HH + t], acc);
  hb[(size_t)blk * HH + t] = f2bf(acc);

  if (blk < 500) {
    int e = blk * 128 + t;
    int src = ei[e], dst = ei[NE + e];
    atomicAdd(&deg[dst], 1.0f);
    int slot = atomicAdd(&cnt[src], 1);
    int p = src * CAP + slot;
    *(float4*)&ea_s[(size_t)p * 4] = *(const float4*)&ea[(size_t)e * 4];
    dst_s[p] = dst;
  } else if (blk < 756) {
    int r = blk - 500;            // 0..255
    int l = r >> 7, k = r & 127;
    const float* w2row = W2 + (size_t)l * (HH * HH * MM) + (size_t)k * 2048;
    float4 v0 = *(const float4*)&w2row[t * 16 + 0];
    float4 v1 = *(const float4*)&w2row[t * 16 + 4];
    float4 v2 = *(const float4*)&w2row[t * 16 + 8];
    float4 v3 = *(const float4*)&w2row[t * 16 + 12];
    unsigned short* bpr = Bp + ((size_t)l * BPR + (size_t)k * 16) * HH + t;
#pragma unroll
    for (int j = 0; j < 4; ++j) bpr[(0 + j) * HH] = f2bf((&v0.x)[j]);
#pragma unroll
    for (int j = 0; j < 4; ++j) bpr[(4 + j) * HH] = f2bf((&v1.x)[j]);
#pragma unroll
    for (int j = 0; j < 4; ++j) bpr[(8 + j) * HH] = f2bf((&v2.x)[j]);
#pragma unroll
    for (int j = 0; j < 4; ++j) bpr[(12 + j) * HH] = f2bf((&v3.x)[j]);
  } else if (blk < 760) {
    int isroot = (blk >= 758);
    int l = (blk - 756) & 1;
    const float* src = isroot ? (rW + (size_t)l * HH * MM) : (b2 + (size_t)l * 2048);
    float4 v0 = *(const float4*)&src[t * 16 + 0];
    float4 v1 = *(const float4*)&src[t * 16 + 4];
    float4 v2 = *(const float4*)&src[t * 16 + 8];
    float4 v3 = *(const float4*)&src[t * 16 + 12];
    unsigned short* bpr = Bp + ((size_t)l * BPR + 2048 + isroot * 16) * HH + t;
#pragma unroll
    for (int j = 0; j < 4; ++j) bpr[(0 + j) * HH] = f2bf((&v0.x)[j]);
#pragma unroll
    for (int j = 0; j < 4; ++j) bpr[(4 + j) * HH] = f2bf((&v1.x)[j]);
#pragma unroll
    for (int j = 0; j < 4; ++j) bpr[(8 + j) * HH] = f2bf((&v2.x)[j]);
#pragma unroll
    for (int j = 0; j < 4; ++j) bpr[(12 + j) * HH] = f2bf((&v3.x)[j]);
  } else if (blk < 885) {
    int i = (blk - 760) * 256 + t;
    uint4 z = make_uint4(0, 0, 0, 0);
    ((uint4*)agg)[i] = z;
    ((uint4*)agg)[i + 128] = z;
  }
}

// Fused layer, 32 src nodes per block, 1024 threads (16 waves, 4/SIMD).
// GEMM phase: explicit 3-deep software pipeline (sched_barrier-pinned) so B-frag
// L2 loads stay ~2 steps ahead of their MFMAs.
__global__ __launch_bounds__(1024) void fused_layer_k(
    const unsigned short* __restrict__ hb, const float* __restrict__ hpre,
    const float* __restrict__ bnsums, const float* __restrict__ gamma,
    const float* __restrict__ beta, int bn_mode,
    const unsigned short* __restrict__ Bp,
    const float* __restrict__ ea_s, const int* __restrict__ dst_s,
    const int* __restrict__ cnt, const float* __restrict__ W1,
    const float* __restrict__ b1, float* __restrict__ agg,
    float* __restrict__ Xroot) {
  __shared__ unsigned short sA[2 * 16 * 136];
  __shared__ unsigned short sQ[2 * 16 * QS];
  __shared__ float sW1[EDF * HH];
  __shared__ float sb1[HH];
  __shared__ float sB2[32][17];
  __shared__ float sscl[HH], sshf[HH];

  int tid = threadIdx.x;
  int n0 = blockIdx.x * 32;
  int wid = tid >> 6, lane = tid & 63;
  int l15 = lane & 15, l4 = lane >> 4;

  for (int i = tid; i < EDF * HH; i += 1024) sW1[i] = W1[i];
  if (tid < HH) sb1[tid] = b1[tid];
  if (bn_mode && tid >= 128 && tid < 256) {
    int c = tid - 128;
    float mu = bnsums[c] * (1.0f / NN);
    float var = bnsums[HH + c] * (1.0f / NN) - mu * mu;
    float sc = gamma[c] * rsqrtf(var + BN_EPS);
    sscl[c] = sc;
    sshf[c] = beta[c] - mu * sc;
  }
  __syncthreads();

  // stage both A tiles (threads 0..511)
  if (tid < 512) {
    int g = tid >> 8;
    int node = (tid >> 4) & 15;
    int c0 = (tid & 15) * 8;
    int ng = n0 + g * 16 + node;
    if (bn_mode == 0) {
      uint4 v = *(const uint4*)&hb[(size_t)ng * HH + c0];
      *(uint4*)&sA[g * 2176 + node * 136 + c0] = v;
    } else {
      float4 v0 = *(const float4*)&hpre[(size_t)ng * HH + c0];
      float4 v1 = *(const float4*)&hpre[(size_t)ng * HH + c0 + 4];
      short8 o;
#pragma unroll
      for (int j = 0; j < 4; ++j) {
        o[j] = (short)f2bf(fmaxf(0.f, fmaf((&v0.x)[j], sscl[c0 + j], sshf[c0 + j])));
        o[4 + j] = (short)f2bf(fmaxf(0.f, fmaf((&v1.x)[j], sscl[c0 + 4 + j], sshf[c0 + 4 + j])));
      }
      *(short8*)&sA[g * 2176 + node * 136 + c0] = o;
    }
  }
  __syncthreads();

  short8 A0 = *(const short8*)&sA[l15 * 136 + 0 * 32 + l4 * 8];
  short8 A1 = *(const short8*)&sA[l15 * 136 + 1 * 32 + l4 * 8];
  short8 A2 = *(const short8*)&sA[l15 * 136 + 2 * 32 + l4 * 8];
  short8 A3 = *(const short8*)&sA[l15 * 136 + 3 * 32 + l4 * 8];
  short8 A4 = *(const short8*)&sA[2176 + l15 * 136 + 0 * 32 + l4 * 8];
  short8 A5 = *(const short8*)&sA[2176 + l15 * 136 + 1 * 32 + l4 * 8];
  short8 A6 = *(const short8*)&sA[2176 + l15 * 136 + 2 * 32 + l4 * 8];
  short8 A7 = *(const short8*)&sA[2176 + l15 * 136 + 3 * 32 + l4 * 8];

  // ---- GEMM phase: ctiles [wid*8, wid*8+8), 3-deep pipelined ----
  int ctb = wid * 8;

#define LDB4(a_, b_, c_, d_, CT)                                              \
  do {                                                                        \
    const unsigned short* p_ = Bp + ((size_t)((CT) * 16 + l15)) * HH + l4 * 8;\
    a_ = *(const short8*)(p_);                                                \
    b_ = *(const short8*)(p_ + 32);                                           \
    c_ = *(const short8*)(p_ + 64);                                           \
    d_ = *(const short8*)(p_ + 96);                                           \
  } while (0)

#define STEP(a_, b_, c_, d_, CT)                                              \
  do {                                                                        \
    f32x4 pa_ = {0.f, 0.f, 0.f, 0.f};                                         \
    f32x4 qa_ = {0.f, 0.f, 0.f, 0.f};                                         \
    pa_ = __builtin_amdgcn_mfma_f32_16x16x32_bf16(A0, a_, pa_, 0, 0, 0);      \
    pa_ = __builtin_amdgcn_mfma_f32_16x16x32_bf16(A1, b_, pa_, 0, 0, 0);      \
    pa_ = __builtin_amdgcn_mfma_f32_16x16x32_bf16(A2, c_, pa_, 0, 0, 0);      \
    pa_ = __builtin_amdgcn_mfma_f32_16x16x32_bf16(A3, d_, pa_, 0, 0, 0);      \
    qa_ = __builtin_amdgcn_mfma_f32_16x16x32_bf16(A4, a_, qa_, 0, 0, 0);      \
    qa_ = __builtin_amdgcn_mfma_f32_16x16x32_bf16(A5, b_, qa_, 0, 0, 0);      \
    qa_ = __builtin_amdgcn_mfma_f32_16x16x32_bf16(A6, c_, qa_, 0, 0, 0);      \
    qa_ = __builtin_amdgcn_mfma_f32_16x16x32_bf16(A7, d_, qa_, 0, 0, 0);      \
    int kq_ = qperm(CT) * 16 + l15;                                           \
    sQ[(l4 * 4 + 0) * QS + kq_] = f2bf(pa_[0]);                               \
    sQ[(l4 * 4 + 1) * QS + kq_] = f2bf(pa_[1]);                               \
    sQ[(l4 * 4 + 2) * QS + kq_] = f2bf(pa_[2]);                               \
    sQ[(l4 * 4 + 3) * QS + kq_] = f2bf(pa_[3]);                               \
    sQ[16 * QS + (l4 * 4 + 0) * QS + kq_] = f2bf(qa_[0]);                     \
    sQ[16 * QS + (l4 * 4 + 1) * QS + kq_] = f2bf(qa_[1]);                     \
    sQ[16 * QS + (l4 * 4 + 2) * QS + kq_] = f2bf(qa_[2]);                     \
    sQ[16 * QS + (l4 * 4 + 3) * QS + kq_] = f2bf(qa_[3]);                     \
  } while (0)

  {
    short8 u0, u1, u2, u3, v0, v1, v2, v3, w0, w1, w2, w3;
    LDB4(u0, u1, u2, u3, ctb + 0);
    LDB4(v0, v1, v2, v3, ctb + 1);
    LDB4(w0, w1, w2, w3, ctb + 2);
    __builtin_amdgcn_sched_barrier(0);
    __builtin_amdgcn_s_setprio(1);
    STEP(u0, u1, u2, u3, ctb + 0);
    LDB4(u0, u1, u2, u3, ctb + 3);
    __builtin_amdgcn_sched_barrier(0);
    STEP(v0, v1, v2, v3, ctb + 1);
    LDB4(v0, v1, v2, v3, ctb + 4);
    __builtin_amdgcn_sched_barrier(0);
    STEP(w0, w1, w2, w3, ctb + 2);
    LDB4(w0, w1, w2, w3, ctb + 5);
    __builtin_amdgcn_sched_barrier(0);
    STEP(u0, u1, u2, u3, ctb + 3);
    LDB4(u0, u1, u2, u3, ctb + 6);
    __builtin_amdgcn_sched_barrier(0);
    STEP(v0, v1, v2, v3, ctb + 4);
    LDB4(v0, v1, v2, v3, ctb + 7);
    __builtin_amdgcn_sched_barrier(0);
    STEP(w0, w1, w2, w3, ctb + 5);
    STEP(u0, u1, u2, u3, ctb + 6);
    STEP(v0, v1, v2, v3, ctb + 7);
    __builtin_amdgcn_s_setprio(0);
  }
#undef STEP
#undef LDB4

  // extra ctiles: wave 14 -> B2 (rows 2048..2063, LDS); wave 15 -> Xroot (global)
  if (wid >= 14) {
    int base = (wid == 14) ? 2048 : 2064;
    const unsigned short* p = Bp + ((size_t)(base + l15)) * HH + l4 * 8;
    short8 c0 = *(const short8*)(p);
    short8 c1 = *(const short8*)(p + 32);
    short8 c2 = *(const short8*)(p + 64);
    short8 c3 = *(const short8*)(p + 96);
    f32x4 pa = {0.f, 0.f, 0.f, 0.f};
    f32x4 qa = {0.f, 0.f, 0.f, 0.f};
    pa = __builtin_amdgcn_mfma_f32_16x16x32_bf16(A0, c0, pa, 0, 0, 0);
    pa = __builtin_amdgcn_mfma_f32_16x16x32_bf16(A1, c1, pa, 0, 0, 0);
    pa = __builtin_amdgcn_mfma_f32_16x16x32_bf16(A2, c2, pa, 0, 0, 0);
    pa = __builtin_amdgcn_mfma_f32_16x16x32_bf16(A3, c3, pa, 0, 0, 0);
    qa = __builtin_amdgcn_mfma_f32_16x16x32_bf16(A4, c0, qa, 0, 0, 0);
    qa = __builtin_amdgcn_mfma_f32_16x16x32_bf16(A5, c1, qa, 0, 0, 0);
    qa = __builtin_amdgcn_mfma_f32_16x16x32_bf16(A6, c2, qa, 0, 0, 0);
    qa = __builtin_amdgcn_mfma_f32_16x16x32_bf16(A7, c3, qa, 0, 0, 0);
    if (wid == 14) {
#pragma unroll
      for (int j = 0; j < 4; ++j) {
        sB2[l4 * 4 + j][l15] = pa[j];
        sB2[16 + l4 * 4 + j][l15] = qa[j];
      }
    } else {
#pragma unroll
      for (int j = 0; j < 4; ++j) {
        Xroot[(size_t)(n0 + l4 * 4 + j) * MM + l15] = pa[j];
        Xroot[(size_t)(n0 + 16 + l4 * 4 + j) * MM + l15] = qa[j];
      }
    }
  }
  __syncthreads();

  // ---- Contract phase: wave handles 2 nodes (1 in each group) ----
  for (int gi = 0; gi < 2; ++gi) {
    int nl = gi * 16 + wid;
    int n = n0 + nl;
    int count = cnt[n];
    if (count == 0) continue;

    const unsigned short* sq = &sQ[gi * 16 * QS + (nl & 15) * QS];
    short8 qb0, qb1, qb2, qb3;
#pragma unroll
    for (int j = 0; j < 8; ++j) {
      qb0[j] = (short)sq[qperm(0 * 32 + l4 * 8 + j) * 16 + l15];
      qb1[j] = (short)sq[qperm(1 * 32 + l4 * 8 + j) * 16 + l15];
      qb2[j] = (short)sq[qperm(2 * 32 + l4 * 8 + j) * 16 + l15];
      qb3[j] = (short)sq[qperm(3 * 32 + l4 * 8 + j) * 16 + l15];
    }
    float b2v = sB2[nl][l15];

    const float* eab = ea_s + (size_t)n * CAP * 4;
    const int* dsb = dst_s + (size_t)n * CAP;
    for (int t0 = 0; t0 < count; t0 += 16) {
      int rr = t0 + l15;
      bool valid = rr < count;
      float4 eav = valid ? *(const float4*)&eab[(size_t)rr * 4]
                         : make_float4(0.f, 0.f, 0.f, 0.f);
      f32x4 acc = {0.f, 0.f, 0.f, 0.f};
#pragma unroll
      for (int ks = 0; ks < 4; ++ks) {
        short8 a;
#pragma unroll
        for (int j = 0; j < 8; ++j) {
          int k = ks * 32 + l4 * 8 + j;
          float r = fmaf(eav.w, sW1[3 * HH + k],
                     fmaf(eav.z, sW1[2 * HH + k],
                       fmaf(eav.y, sW1[HH + k], fmaf(eav.x, sW1[k], sb1[k]))));
          a[j] = valid ? (short)f2bf(fmaxf(r, 0.f)) : (short)0;
        }
        short8 qb = (ks == 0) ? qb0 : (ks == 1) ? qb1 : (ks == 2) ? qb2 : qb3;
        acc = __builtin_amdgcn_mfma_f32_16x16x32_bf16(a, qb, acc, 0, 0, 0);
      }
#pragma unroll
      for (int j = 0; j < 4; ++j) {
        int r = t0 + l4 * 4 + j;
        if (r < count) {
          atomicAdd(&agg[(size_t)dsb[r] * MM + l15], acc[j] + b2v);
        }
      }
    }
  }
}

// 16 nodes/block: xm = agg/deg + Xroot + cbias ; hp = resid + xm@msgW + msgb
// fused BN partial sums; zeroes its agg slice for next layer.
__global__ __launch_bounds__(256) void node_update_k(
    const unsigned short* __restrict__ hb, const float* __restrict__ hsrc_pre,
    const float* __restrict__ bnsums, const float* __restrict__ gamma,
    const float* __restrict__ beta, int bn_mode,
    float* __restrict__ agg, const float* __restrict__ deg,
    const float* __restrict__ Xroot, const float* __restrict__ cbias,
    const float* __restrict__ msgW, const float* __restrict__ msgb,
    float* __restrict__ hpre, float* __restrict__ sums) {
  __shared__ float smw[MM * HH];
  __shared__ float xm[16][MM];
  __shared__ float scb[MM];
  __shared__ float smb[HH];
  __shared__ float red[256];
  __shared__ float sscl[HH], sshf[HH];
  int tid = threadIdx.x;
  int n0 = blockIdx.x * 16;
  for (int i = tid; i < MM * HH; i += 256) smw[i] = msgW[i];
  if (tid < MM) scb[tid] = cbias[tid];
  if (tid < HH) smb[tid] = msgb[tid];
  if (bn_mode && tid < HH) {
    float mu = bnsums[tid] * (1.0f / NN);
    float var = bnsums[HH + tid] * (1.0f / NN) - mu * mu;
    float sc = gamma[tid] * rsqrtf(var + BN_EPS);
    sscl[tid] = sc;
    sshf[tid] = beta[tid] - mu * sc;
  }
  __syncthreads();

  {
    int ni = tid >> 4, m = tid & 15;
    int n = n0 + ni;
    size_t idx = (size_t)n * MM + m;
    xm[ni][m] = agg[idx] / fmaxf(deg[n], 1.0f) + Xroot[idx] + scb[m];
  }
  __syncthreads();
  agg[(size_t)n0 * MM + tid] = 0.f;

  int t = tid & 127;
  float lsum = 0.f, lss = 0.f;
#pragma unroll
  for (int pass = 0; pass < 8; ++pass) {
    int ni = pass * 2 + (tid >> 7);
    size_t idx = (size_t)(n0 + ni) * HH + t;
    float resid;
    if (bn_mode) {
      resid = fmaxf(0.f, fmaf(hsrc_pre[idx], sscl[t], sshf[t]));
    } else {
      resid = bf2f(hb[idx]);
    }
    float hp = resid + smb[t];
#pragma unroll
    for (int m = 0; m < MM; ++m) hp = fmaf(xm[ni][m], smw[m * HH + t], hp);
    hpre[idx] = hp;
    lsum += hp;
    lss = fmaf(hp, hp, lss);
  }
  red[tid] = lsum;
  __syncthreads();
  if (tid < 128) atomicAdd(&sums[t], red[tid] + red[tid + 128]);
  __syncthreads();
  red[tid] = lss;
  __syncthreads();
  if (tid < 128) atomicAdd(&sums[HH + t], red[tid] + red[tid + 128]);
}

__global__ void out_proj_k(const float* __restrict__ hpre,
                           const float* __restrict__ bnsums,
                           const float* __restrict__ gamma,
                           const float* __restrict__ beta,
                           const float* __restrict__ W, const float* __restrict__ b,
                           float* __restrict__ out) {
  __shared__ float sscl[HH], sshf[HH];
  int tid = threadIdx.x;
  if (tid < HH) {
    float mu = bnsums[tid] * (1.0f / NN);
    float var = bnsums[HH + tid] * (1.0f / NN) - mu * mu;
    float sc = gamma[tid] * rsqrtf(var + BN_EPS);
    sscl[tid] = sc;
    sshf[tid] = beta[tid] - mu * sc;
  }
  __syncthreads();
  int n = blockIdx.x * 4 + (tid >> 6);
  int lane = tid & 63;
  if (n >= NN) return;
  float acc0 = 0.f, acc1 = 0.f, acc2 = 0.f, acc3 = 0.f;
#pragma unroll
  for (int rep = 0; rep < 2; ++rep) {
    int hh = lane + rep * 64;
    float hv = fmaxf(0.f, fmaf(hpre[(size_t)n * HH + hh], sscl[hh], sshf[hh]));
    acc0 = fmaf(hv, W[hh * OUTF + 0], acc0);
    acc1 = fmaf(hv, W[hh * OUTF + 1], acc1);
    acc2 = fmaf(hv, W[hh * OUTF + 2], acc2);
    acc3 = fmaf(hv, W[hh * OUTF + 3], acc3);
  }
#pragma unroll
  for (int s = 32; s > 0; s >>= 1) {
    acc0 += __shfl_down(acc0, s);
    acc1 += __shfl_down(acc1, s);
    acc2 += __shfl_down(acc2, s);
    acc3 += __shfl_down(acc3, s);
  }
  if (lane == 0) {
    out[n * OUTF + 0] = acc0 + b[0];
    out[n * OUTF + 1] = acc1 + b[1];
    out[n * OUTF + 2] = acc2 + b[2];
    out[n * OUTF + 3] = acc3 + b[3];
  }
}

extern "C" void kernel_launch(void* const* d_in, const int* in_sizes, int n_in,
                              void* d_out, int out_size, void* d_ws, size_t ws_size,
                              hipStream_t stream) {
  (void)in_sizes; (void)n_in; (void)out_size; (void)ws_size;
  const float* x    = (const float*)d_in[0];
  const int* ei     = (const int*)d_in[1];
  const float* ea   = (const float*)d_in[2];
  const float* inW  = (const float*)d_in[3];
  const float* inb  = (const float*)d_in[4];
  const float* cW1  = (const float*)d_in[5];
  const float* cb1  = (const float*)d_in[6];
  const float* cW2  = (const float*)d_in[7];
  const float* cb2  = (const float*)d_in[8];
  const float* rW   = (const float*)d_in[9];
  const float* cbias= (const float*)d_in[10];
  const float* gam  = (const float*)d_in[11];
  const float* bet  = (const float*)d_in[12];
  const float* mW   = (const float*)d_in[13];
  const float* mb   = (const float*)d_in[14];
  const float* oW   = (const float*)d_in[15];
  const float* ob   = (const float*)d_in[16];
  float* out = (float*)d_out;

  float* ws = (float*)d_ws;
  size_t off = 0;
  // contiguous zero region: deg, cnt, sums0, sums1 (one small memset)
  float* deg   = ws + off; off += 8192;
  int* cnt     = (int*)(ws + off); off += 8192;
  float* sums0 = ws + off; off += 256;
  float* sums1 = ws + off; off += 256;
  size_t zero_floats = off;
  float* agg   = ws + off; off += (size_t)NN * MM;      // zeroed by front_k
  float* hpre0 = ws + off; off += (size_t)NN * HH;
  float* hpre1 = ws + off; off += (size_t)NN * HH;
  float* Xroot = ws + off; off += (size_t)NN * MM;
  unsigned short* hb = (unsigned short*)(ws + off); off += (size_t)NN * HH / 2;
  unsigned short* Bp = (unsigned short*)(ws + off); off += (size_t)NL * BPR * HH / 2;
  float* ea_s  = ws + off; off += (size_t)NN * CAP * 4;
  int* dst_s   = (int*)(ws + off); off += (size_t)NN * CAP;

  hipMemsetAsync(deg, 0, zero_floats * sizeof(float), stream);
  front_k<<<NN, 128, 0, stream>>>(x, inW, inb, ei, ea, cW2, cb2, rW, hb,
                                  deg, cnt, Bp, agg, ea_s, dst_s);

  // ---- layer 0 ----
  fused_layer_k<<<NN / 32, 1024, 0, stream>>>(hb, hpre0, sums0, gam, bet, 0,
                                              Bp, ea_s, dst_s, cnt, cW1, cb1,
                                              agg, Xroot);
  node_update_k<<<NN / 16, 256, 0, stream>>>(hb, hpre0, sums0, gam, bet, 0,
                                             agg, deg, Xroot, cbias, mW, mb,
                                             hpre0, sums0);
  // ---- layer 1 ----
  fused_layer_k<<<NN / 32, 1024, 0, stream>>>(hb, hpre0, sums0, gam, bet, 1,
                                              Bp + (size_t)BPR * HH, ea_s, dst_s,
                                              cnt, cW1 + EDF * HH, cb1 + HH,
                                              agg, Xroot);
  node_update_k<<<NN / 16, 256, 0, stream>>>(hb, hpre0, sums0, gam, bet, 1,
                                             agg, deg, Xroot, cbias + MM,
                                             mW + MM * HH, mb + HH,
                                             hpre1, sums1);
  out_proj_k<<<NN / 4, 256, 0, stream>>>(hpre1, sums1, gam + HH, bet + HH,
                                         oW, ob, out);
}

// Round 18
// 119.906 us; speedup vs baseline: 1.2656x; 1.0062x over previous
//
#include <hip/hip_runtime.h>

#define NN 8000
#define NE 64000
#define INF 16
#define HH 128
#define MM 16
#define EDF 4
#define OUTF 4
#define NL 2
#define BN_EPS 1e-5f
#define BPR 2080          // Bp rows per layer: 2048 qn + 16 b2 + 16 rootW
#define CAP 48            // per-node edge bucket capacity
#define QS 2052           // sQ node stride in halfs

typedef __attribute__((ext_vector_type(8))) short short8;
typedef __attribute__((ext_vector_type(4))) float f32x4;

static __device__ __forceinline__ unsigned short f2bf(float f) {
  unsigned u = __builtin_bit_cast(unsigned, f);
  u = (u + 0x7fffu + ((u >> 16) & 1u)) >> 16;
  return (unsigned short)u;
}
static __device__ __forceinline__ float bf2f(unsigned short s) {
  unsigned u = ((unsigned)s) << 16;
  return __builtin_bit_cast(float, u);
}
static __device__ __forceinline__ int qperm(int k) {
  return ((k >> 3) & 3) | ((k & 7) << 2) | (k & 0x60);
}

// edge bucket-scatter (0..499) + Bp build (500..759) + agg zero (760..884)
__global__ __launch_bounds__(128) void front_k(
    const int* __restrict__ ei, const float* __restrict__ ea,
    const float* __restrict__ W2, const float* __restrict__ b2,
    const float* __restrict__ rW,
    float* __restrict__ deg, int* __restrict__ cnt,
    unsigned short* __restrict__ Bp, float* __restrict__ agg,
    float* __restrict__ ea_s, int* __restrict__ dst_s) {
  int blk = blockIdx.x;
  int t = threadIdx.x;

  if (blk < 500) {
    int e = blk * 128 + t;
    int src = ei[e], dst = ei[NE + e];
    atomicAdd(&deg[dst], 1.0f);
    int slot = atomicAdd(&cnt[src], 1);
    int p = src * CAP + slot;
    *(float4*)&ea_s[(size_t)p * 4] = *(const float4*)&ea[(size_t)e * 4];
    dst_s[p] = dst;
  } else if (blk < 756) {
    int r = blk - 500;            // 0..255
    int l = r >> 7, k = r & 127;
    const float* w2row = W2 + (size_t)l * (HH * HH * MM) + (size_t)k * 2048;
    float4 v0 = *(const float4*)&w2row[t * 16 + 0];
    float4 v1 = *(const float4*)&w2row[t * 16 + 4];
    float4 v2 = *(const float4*)&w2row[t * 16 + 8];
    float4 v3 = *(const float4*)&w2row[t * 16 + 12];
    unsigned short* bpr = Bp + ((size_t)l * BPR + (size_t)k * 16) * HH + t;
#pragma unroll
    for (int j = 0; j < 4; ++j) bpr[(0 + j) * HH] = f2bf((&v0.x)[j]);
#pragma unroll
    for (int j = 0; j < 4; ++j) bpr[(4 + j) * HH] = f2bf((&v1.x)[j]);
#pragma unroll
    for (int j = 0; j < 4; ++j) bpr[(8 + j) * HH] = f2bf((&v2.x)[j]);
#pragma unroll
    for (int j = 0; j < 4; ++j) bpr[(12 + j) * HH] = f2bf((&v3.x)[j]);
  } else if (blk < 760) {
    int isroot = (blk >= 758);
    int l = (blk - 756) & 1;
    const float* src = isroot ? (rW + (size_t)l * HH * MM) : (b2 + (size_t)l * 2048);
    float4 v0 = *(const float4*)&src[t * 16 + 0];
    float4 v1 = *(const float4*)&src[t * 16 + 4];
    float4 v2 = *(const float4*)&src[t * 16 + 8];
    float4 v3 = *(const float4*)&src[t * 16 + 12];
    unsigned short* bpr = Bp + ((size_t)l * BPR + 2048 + isroot * 16) * HH + t;
#pragma unroll
    for (int j = 0; j < 4; ++j) bpr[(0 + j) * HH] = f2bf((&v0.x)[j]);
#pragma unroll
    for (int j = 0; j < 4; ++j) bpr[(4 + j) * HH] = f2bf((&v1.x)[j]);
#pragma unroll
    for (int j = 0; j < 4; ++j) bpr[(8 + j) * HH] = f2bf((&v2.x)[j]);
#pragma unroll
    for (int j = 0; j < 4; ++j) bpr[(12 + j) * HH] = f2bf((&v3.x)[j]);
  } else if (blk < 885) {
    int i = (blk - 760) * 256 + t;
    uint4 z = make_uint4(0, 0, 0, 0);
    ((uint4*)agg)[i] = z;
    ((uint4*)agg)[i + 128] = z;
  }
}

// Fused layer, 32 src nodes per block, 1024 threads (16 waves, 4/SIMD).
// Layer 0 (bn_mode==0): A = bf16(x @ inW + inb) computed INLINE (writes hb too).
// Layer 1 (bn_mode==1): A = bf16(BN_relu(hpre)).
// GEMM phase: 3-deep pinned pipeline; wave14 -> B2 (LDS), wave15 -> Xroot (global).
// Contract phase: per-node P = relu1 @ Qn_tile[node], atomics into agg.
__global__ __launch_bounds__(1024) void fused_layer_k(
    const float* __restrict__ x, const float* __restrict__ inW,
    const float* __restrict__ inb, unsigned short* __restrict__ hb,
    const float* __restrict__ hpre,
    const float* __restrict__ bnsums, const float* __restrict__ gamma,
    const float* __restrict__ beta, int bn_mode,
    const unsigned short* __restrict__ Bp,
    const float* __restrict__ ea_s, const int* __restrict__ dst_s,
    const int* __restrict__ cnt, const float* __restrict__ W1,
    const float* __restrict__ b1, float* __restrict__ agg,
    float* __restrict__ Xroot) {
  __shared__ unsigned short sA[2 * 16 * 136];
  __shared__ unsigned short sQ[2 * 16 * QS];
  __shared__ float sW1[EDF * HH];
  __shared__ float sb1[HH];
  __shared__ float sB2[32][17];
  __shared__ float sscl[HH], sshf[HH];
  __shared__ float sIW[INF * HH];
  __shared__ float sX[32 * INF];

  int tid = threadIdx.x;
  int n0 = blockIdx.x * 32;
  int wid = tid >> 6, lane = tid & 63;
  int l15 = lane & 15, l4 = lane >> 4;

  for (int i = tid; i < EDF * HH; i += 1024) sW1[i] = W1[i];
  if (tid < HH) sb1[tid] = b1[tid];
  if (bn_mode) {
    if (tid >= 128 && tid < 256) {
      int c = tid - 128;
      float mu = bnsums[c] * (1.0f / NN);
      float var = bnsums[HH + c] * (1.0f / NN) - mu * mu;
      float sc = gamma[c] * rsqrtf(var + BN_EPS);
      sscl[c] = sc;
      sshf[c] = beta[c] - mu * sc;
    }
  } else {
    // stage x block (32 nodes x 16) and inW (16 x 128) + inb into sscl-reuse
    if (tid >= 256 && tid < 768) sX[tid - 256] = x[(size_t)n0 * INF + (tid - 256)];
    if (tid >= 768 && tid < 896) sscl[tid - 768] = inb[tid - 768];
    for (int i = tid & 1023; i < INF * HH; i += 1024) sIW[i] = inW[i];
  }
  __syncthreads();

  // stage both A tiles
  if (bn_mode == 0) {
    // thread t: node t>>5 (0..31), cols (t&31)*4 .. +4 ; inline in_proj
    int nl = tid >> 5;
    int c0 = (tid & 31) * 4;
    int g = nl >> 4;
    ushort4 o;
#pragma unroll
    for (int j = 0; j < 4; ++j) {
      int c = c0 + j;
      float acc = sscl[c];  // inb
#pragma unroll
      for (int i = 0; i < INF; ++i) acc = fmaf(sX[nl * INF + i], sIW[i * HH + c], acc);
      (&o.x)[j] = f2bf(acc);
    }
    *(ushort4*)&sA[g * 2176 + (nl & 15) * 136 + c0] = o;
    *(ushort4*)&hb[(size_t)(n0 + nl) * HH + c0] = o;
  } else if (tid < 512) {
    int g = tid >> 8;
    int node = (tid >> 4) & 15;
    int c0 = (tid & 15) * 8;
    int ng = n0 + g * 16 + node;
    float4 v0 = *(const float4*)&hpre[(size_t)ng * HH + c0];
    float4 v1 = *(const float4*)&hpre[(size_t)ng * HH + c0 + 4];
    short8 o;
#pragma unroll
    for (int j = 0; j < 4; ++j) {
      o[j] = (short)f2bf(fmaxf(0.f, fmaf((&v0.x)[j], sscl[c0 + j], sshf[c0 + j])));
      o[4 + j] = (short)f2bf(fmaxf(0.f, fmaf((&v1.x)[j], sscl[c0 + 4 + j], sshf[c0 + 4 + j])));
    }
    *(short8*)&sA[g * 2176 + node * 136 + c0] = o;
  }
  __syncthreads();

  short8 A0 = *(const short8*)&sA[l15 * 136 + 0 * 32 + l4 * 8];
  short8 A1 = *(const short8*)&sA[l15 * 136 + 1 * 32 + l4 * 8];
  short8 A2 = *(const short8*)&sA[l15 * 136 + 2 * 32 + l4 * 8];
  short8 A3 = *(const short8*)&sA[l15 * 136 + 3 * 32 + l4 * 8];
  short8 A4 = *(const short8*)&sA[2176 + l15 * 136 + 0 * 32 + l4 * 8];
  short8 A5 = *(const short8*)&sA[2176 + l15 * 136 + 1 * 32 + l4 * 8];
  short8 A6 = *(const short8*)&sA[2176 + l15 * 136 + 2 * 32 + l4 * 8];
  short8 A7 = *(const short8*)&sA[2176 + l15 * 136 + 3 * 32 + l4 * 8];

  // ---- GEMM phase: ctiles [wid*8, wid*8+8), 3-deep pipelined ----
  int ctb = wid * 8;

#define LDB4(a_, b_, c_, d_, CT)                                              \
  do {                                                                        \
    const unsigned short* p_ = Bp + ((size_t)((CT) * 16 + l15)) * HH + l4 * 8;\
    a_ = *(const short8*)(p_);                                                \
    b_ = *(const short8*)(p_ + 32);                                           \
    c_ = *(const short8*)(p_ + 64);                                           \
    d_ = *(const short8*)(p_ + 96);                                           \
  } while (0)

#define STEP(a_, b_, c_, d_, CT)                                              \
  do {                                                                        \
    f32x4 pa_ = {0.f, 0.f, 0.f, 0.f};                                         \
    f32x4 qa_ = {0.f, 0.f, 0.f, 0.f};                                         \
    pa_ = __builtin_amdgcn_mfma_f32_16x16x32_bf16(A0, a_, pa_, 0, 0, 0);      \
    pa_ = __builtin_amdgcn_mfma_f32_16x16x32_bf16(A1, b_, pa_, 0, 0, 0);      \
    pa_ = __builtin_amdgcn_mfma_f32_16x16x32_bf16(A2, c_, pa_, 0, 0, 0);      \
    pa_ = __builtin_amdgcn_mfma_f32_16x16x32_bf16(A3, d_, pa_, 0, 0, 0);      \
    qa_ = __builtin_amdgcn_mfma_f32_16x16x32_bf16(A4, a_, qa_, 0, 0, 0);      \
    qa_ = __builtin_amdgcn_mfma_f32_16x16x32_bf16(A5, b_, qa_, 0, 0, 0);      \
    qa_ = __builtin_amdgcn_mfma_f32_16x16x32_bf16(A6, c_, qa_, 0, 0, 0);      \
    qa_ = __builtin_amdgcn_mfma_f32_16x16x32_bf16(A7, d_, qa_, 0, 0, 0);      \
    int kq_ = qperm(CT) * 16 + l15;                                           \
    sQ[(l4 * 4 + 0) * QS + kq_] = f2bf(pa_[0]);                               \
    sQ[(l4 * 4 + 1) * QS + kq_] = f2bf(pa_[1]);                               \
    sQ[(l4 * 4 + 2) * QS + kq_] = f2bf(pa_[2]);                               \
    sQ[(l4 * 4 + 3) * QS + kq_] = f2bf(pa_[3]);                               \
    sQ[16 * QS + (l4 * 4 + 0) * QS + kq_] = f2bf(qa_[0]);                     \
    sQ[16 * QS + (l4 * 4 + 1) * QS + kq_] = f2bf(qa_[1]);                     \
    sQ[16 * QS + (l4 * 4 + 2) * QS + kq_] = f2bf(qa_[2]);                     \
    sQ[16 * QS + (l4 * 4 + 3) * QS + kq_] = f2bf(qa_[3]);                     \
  } while (0)

  {
    short8 u0, u1, u2, u3, v0, v1, v2, v3, w0, w1, w2, w3;
    LDB4(u0, u1, u2, u3, ctb + 0);
    LDB4(v0, v1, v2, v3, ctb + 1);
    LDB4(w0, w1, w2, w3, ctb + 2);
    __builtin_amdgcn_sched_barrier(0);
    __builtin_amdgcn_s_setprio(1);
    STEP(u0, u1, u2, u3, ctb + 0);
    LDB4(u0, u1, u2, u3, ctb + 3);
    __builtin_amdgcn_sched_barrier(0);
    STEP(v0, v1, v2, v3, ctb + 1);
    LDB4(v0, v1, v2, v3, ctb + 4);
    __builtin_amdgcn_sched_barrier(0);
    STEP(w0, w1, w2, w3, ctb + 2);
    LDB4(w0, w1, w2, w3, ctb + 5);
    __builtin_amdgcn_sched_barrier(0);
    STEP(u0, u1, u2, u3, ctb + 3);
    LDB4(u0, u1, u2, u3, ctb + 6);
    __builtin_amdgcn_sched_barrier(0);
    STEP(v0, v1, v2, v3, ctb + 4);
    LDB4(v0, v1, v2, v3, ctb + 7);
    __builtin_amdgcn_sched_barrier(0);
    STEP(w0, w1, w2, w3, ctb + 5);
    STEP(u0, u1, u2, u3, ctb + 6);
    STEP(v0, v1, v2, v3, ctb + 7);
    __builtin_amdgcn_s_setprio(0);
  }
#undef STEP
#undef LDB4

  // extra ctiles: wave 14 -> B2 (rows 2048..2063, LDS); wave 15 -> Xroot (global)
  if (wid >= 14) {
    int base = (wid == 14) ? 2048 : 2064;
    const unsigned short* p = Bp + ((size_t)(base + l15)) * HH + l4 * 8;
    short8 c0 = *(const short8*)(p);
    short8 c1 = *(const short8*)(p + 32);
    short8 c2 = *(const short8*)(p + 64);
    short8 c3 = *(const short8*)(p + 96);
    f32x4 pa = {0.f, 0.f, 0.f, 0.f};
    f32x4 qa = {0.f, 0.f, 0.f, 0.f};
    pa = __builtin_amdgcn_mfma_f32_16x16x32_bf16(A0, c0, pa, 0, 0, 0);
    pa = __builtin_amdgcn_mfma_f32_16x16x32_bf16(A1, c1, pa, 0, 0, 0);
    pa = __builtin_amdgcn_mfma_f32_16x16x32_bf16(A2, c2, pa, 0, 0, 0);
    pa = __builtin_amdgcn_mfma_f32_16x16x32_bf16(A3, c3, pa, 0, 0, 0);
    qa = __builtin_amdgcn_mfma_f32_16x16x32_bf16(A4, c0, qa, 0, 0, 0);
    qa = __builtin_amdgcn_mfma_f32_16x16x32_bf16(A5, c1, qa, 0, 0, 0);
    qa = __builtin_amdgcn_mfma_f32_16x16x32_bf16(A6, c2, qa, 0, 0, 0);
    qa = __builtin_amdgcn_mfma_f32_16x16x32_bf16(A7, c3, qa, 0, 0, 0);
    if (wid == 14) {
#pragma unroll
      for (int j = 0; j < 4; ++j) {
        sB2[l4 * 4 + j][l15] = pa[j];
        sB2[16 + l4 * 4 + j][l15] = qa[j];
      }
    } else {
#pragma unroll
      for (int j = 0; j < 4; ++j) {
        Xroot[(size_t)(n0 + l4 * 4 + j) * MM + l15] = pa[j];
        Xroot[(size_t)(n0 + 16 + l4 * 4 + j) * MM + l15] = qa[j];
      }
    }
  }
  __syncthreads();

  // ---- Contract phase: wave handles 2 nodes (1 in each group) ----
  for (int gi = 0; gi < 2; ++gi) {
    int nl = gi * 16 + wid;
    int n = n0 + nl;
    int count = cnt[n];
    if (count == 0) continue;

    const unsigned short* sq = &sQ[gi * 16 * QS + (nl & 15) * QS];
    short8 qb0, qb1, qb2, qb3;
#pragma unroll
    for (int j = 0; j < 8; ++j) {
      qb0[j] = (short)sq[qperm(0 * 32 + l4 * 8 + j) * 16 + l15];
      qb1[j] = (short)sq[qperm(1 * 32 + l4 * 8 + j) * 16 + l15];
      qb2[j] = (short)sq[qperm(2 * 32 + l4 * 8 + j) * 16 + l15];
      qb3[j] = (short)sq[qperm(3 * 32 + l4 * 8 + j) * 16 + l15];
    }
    float b2v = sB2[nl][l15];

    const float* eab = ea_s + (size_t)n * CAP * 4;
    const int* dsb = dst_s + (size_t)n * CAP;
    for (int t0 = 0; t0 < count; t0 += 16) {
      int rr = t0 + l15;
      bool valid = rr < count;
      float4 eav = valid ? *(const float4*)&eab[(size_t)rr * 4]
                         : make_float4(0.f, 0.f, 0.f, 0.f);
      f32x4 acc = {0.f, 0.f, 0.f, 0.f};
#pragma unroll
      for (int ks = 0; ks < 4; ++ks) {
        short8 a;
#pragma unroll
        for (int j = 0; j < 8; ++j) {
          int k = ks * 32 + l4 * 8 + j;
          float r = fmaf(eav.w, sW1[3 * HH + k],
                     fmaf(eav.z, sW1[2 * HH + k],
                       fmaf(eav.y, sW1[HH + k], fmaf(eav.x, sW1[k], sb1[k]))));
          a[j] = valid ? (short)f2bf(fmaxf(r, 0.f)) : (short)0;
        }
        short8 qb = (ks == 0) ? qb0 : (ks == 1) ? qb1 : (ks == 2) ? qb2 : qb3;
        acc = __builtin_amdgcn_mfma_f32_16x16x32_bf16(a, qb, acc, 0, 0, 0);
      }
#pragma unroll
      for (int j = 0; j < 4; ++j) {
        int r = t0 + l4 * 4 + j;
        if (r < count) {
          atomicAdd(&agg[(size_t)dsb[r] * MM + l15], acc[j] + b2v);
        }
      }
    }
  }
}

// 16 nodes/block: xm = agg/deg + Xroot + cbias ; hp = resid + xm@msgW + msgb
// fused BN partial sums; zeroes its agg slice for next layer.
__global__ __launch_bounds__(256) void node_update_k(
    const unsigned short* __restrict__ hb, const float* __restrict__ hsrc_pre,
    const float* __restrict__ bnsums, const float* __restrict__ gamma,
    const float* __restrict__ beta, int bn_mode,
    float* __restrict__ agg, const float* __restrict__ deg,
    const float* __restrict__ Xroot, const float* __restrict__ cbias,
    const float* __restrict__ msgW, const float* __restrict__ msgb,
    float* __restrict__ hpre, float* __restrict__ sums) {
  __shared__ float smw[MM * HH];
  __shared__ float xm[16][MM];
  __shared__ float scb[MM];
  __shared__ float smb[HH];
  __shared__ float red[256];
  __shared__ float sscl[HH], sshf[HH];
  int tid = threadIdx.x;
  int n0 = blockIdx.x * 16;
  for (int i = tid; i < MM * HH; i += 256) smw[i] = msgW[i];
  if (tid < MM) scb[tid] = cbias[tid];
  if (tid < HH) smb[tid] = msgb[tid];
  if (bn_mode && tid < HH) {
    float mu = bnsums[tid] * (1.0f / NN);
    float var = bnsums[HH + tid] * (1.0f / NN) - mu * mu;
    float sc = gamma[tid] * rsqrtf(var + BN_EPS);
    sscl[tid] = sc;
    sshf[tid] = beta[tid] - mu * sc;
  }
  __syncthreads();

  {
    int ni = tid >> 4, m = tid & 15;
    int n = n0 + ni;
    size_t idx = (size_t)n * MM + m;
    xm[ni][m] = agg[idx] / fmaxf(deg[n], 1.0f) + Xroot[idx] + scb[m];
  }
  __syncthreads();
  agg[(size_t)n0 * MM + tid] = 0.f;

  int t = tid & 127;
  float lsum = 0.f, lss = 0.f;
#pragma unroll
  for (int pass = 0; pass < 8; ++pass) {
    int ni = pass * 2 + (tid >> 7);
    size_t idx = (size_t)(n0 + ni) * HH + t;
    float resid;
    if (bn_mode) {
      resid = fmaxf(0.f, fmaf(hsrc_pre[idx], sscl[t], sshf[t]));
    } else {
      resid = bf2f(hb[idx]);
    }
    float hp = resid + smb[t];
#pragma unroll
    for (int m = 0; m < MM; ++m) hp = fmaf(xm[ni][m], smw[m * HH + t], hp);
    hpre[idx] = hp;
    lsum += hp;
    lss = fmaf(hp, hp, lss);
  }
  red[tid] = lsum;
  __syncthreads();
  if (tid < 128) atomicAdd(&sums[t], red[tid] + red[tid + 128]);
  __syncthreads();
  red[tid] = lss;
  __syncthreads();
  if (tid < 128) atomicAdd(&sums[HH + t], red[tid] + red[tid + 128]);
}

__global__ void out_proj_k(const float* __restrict__ hpre,
                           const float* __restrict__ bnsums,
                           const float* __restrict__ gamma,
                           const float* __restrict__ beta,
                           const float* __restrict__ W, const float* __restrict__ b,
                           float* __restrict__ out) {
  __shared__ float sscl[HH], sshf[HH];
  int tid = threadIdx.x;
  if (tid < HH) {
    float mu = bnsums[tid] * (1.0f / NN);
    float var = bnsums[HH + tid] * (1.0f / NN) - mu * mu;
    float sc = gamma[tid] * rsqrtf(var + BN_EPS);
    sscl[tid] = sc;
    sshf[tid] = beta[tid] - mu * sc;
  }
  __syncthreads();
  int n = blockIdx.x * 4 + (tid >> 6);
  int lane = tid & 63;
  if (n >= NN) return;
  float acc0 = 0.f, acc1 = 0.f, acc2 = 0.f, acc3 = 0.f;
#pragma unroll
  for (int rep = 0; rep < 2; ++rep) {
    int hh = lane + rep * 64;
    float hv = fmaxf(0.f, fmaf(hpre[(size_t)n * HH + hh], sscl[hh], sshf[hh]));
    acc0 = fmaf(hv, W[hh * OUTF + 0], acc0);
    acc1 = fmaf(hv, W[hh * OUTF + 1], acc1);
    acc2 = fmaf(hv, W[hh * OUTF + 2], acc2);
    acc3 = fmaf(hv, W[hh * OUTF + 3], acc3);
  }
#pragma unroll
  for (int s = 32; s > 0; s >>= 1) {
    acc0 += __shfl_down(acc0, s);
    acc1 += __shfl_down(acc1, s);
    acc2 += __shfl_down(acc2, s);
    acc3 += __shfl_down(acc3, s);
  }
  if (lane == 0) {
    out[n * OUTF + 0] = acc0 + b[0];
    out[n * OUTF + 1] = acc1 + b[1];
    out[n * OUTF + 2] = acc2 + b[2];
    out[n * OUTF + 3] = acc3 + b[3];
  }
}

extern "C" void kernel_launch(void* const* d_in, const int* in_sizes, int n_in,
                              void* d_out, int out_size, void* d_ws, size_t ws_size,
                              hipStream_t stream) {
  (void)in_sizes; (void)n_in; (void)out_size; (void)ws_size;
  const float* x    = (const float*)d_in[0];
  const int* ei     = (const int*)d_in[1];
  const float* ea   = (const float*)d_in[2];
  const float* inW  = (const float*)d_in[3];
  const float* inb  = (const float*)d_in[4];
  const float* cW1  = (const float*)d_in[5];
  const float* cb1  = (const float*)d_in[6];
  const float* cW2  = (const float*)d_in[7];
  const float* cb2  = (const float*)d_in[8];
  const float* rW   = (const float*)d_in[9];
  const float* cbias= (const float*)d_in[10];
  const float* gam  = (const float*)d_in[11];
  const float* bet  = (const float*)d_in[12];
  const float* mW   = (const float*)d_in[13];
  const float* mb   = (const float*)d_in[14];
  const float* oW   = (const float*)d_in[15];
  const float* ob   = (const float*)d_in[16];
  float* out = (float*)d_out;

  float* ws = (float*)d_ws;
  size_t off = 0;
  // contiguous zero region: deg, cnt, sums0, sums1 (one small memset)
  float* deg   = ws + off; off += 8192;
  int* cnt     = (int*)(ws + off); off += 8192;
  float* sums0 = ws + off; off += 256;
  float* sums1 = ws + off; off += 256;
  size_t zero_floats = off;
  float* agg   = ws + off; off += (size_t)NN * MM;      // zeroed by front_k
  float* hpre0 = ws + off; off += (size_t)NN * HH;
  float* hpre1 = ws + off; off += (size_t)NN * HH;
  float* Xroot = ws + off; off += (size_t)NN * MM;
  unsigned short* hb = (unsigned short*)(ws + off); off += (size_t)NN * HH / 2;
  unsigned short* Bp = (unsigned short*)(ws + off); off += (size_t)NL * BPR * HH / 2;
  float* ea_s  = ws + off; off += (size_t)NN * CAP * 4;
  int* dst_s   = (int*)(ws + off); off += (size_t)NN * CAP;

  hipMemsetAsync(deg, 0, zero_floats * sizeof(float), stream);
  front_k<<<885, 128, 0, stream>>>(ei, ea, cW2, cb2, rW, deg, cnt, Bp, agg,
                                   ea_s, dst_s);

  // ---- layer 0 (inline in_proj) ----
  fused_layer_k<<<NN / 32, 1024, 0, stream>>>(x, inW, inb, hb, hpre0,
                                              sums0, gam, bet, 0,
                                              Bp, ea_s, dst_s, cnt, cW1, cb1,
                                              agg, Xroot);
  node_update_k<<<NN / 16, 256, 0, stream>>>(hb, hpre0, sums0, gam, bet, 0,
                                             agg, deg, Xroot, cbias, mW, mb,
                                             hpre0, sums0);
  // ---- layer 1 ----
  fused_layer_k<<<NN / 32, 1024, 0, stream>>>(x, inW, inb, hb, hpre0,
                                              sums0, gam, bet, 1,
                                              Bp + (size_t)BPR * HH, ea_s, dst_s,
                                              cnt, cW1 + EDF * HH, cb1 + HH,
                                              agg, Xroot);
  node_update_k<<<NN / 16, 256, 0, stream>>>(hb, hpre0, sums0, gam, bet, 1,
                                             agg, deg, Xroot, cbias + MM,
                                             mW + MM * HH, mb + HH,
                                             hpre1, sums1);
  out_proj_k<<<NN / 4, 256, 0, stream>>>(hpre1, sums1, gam + HH, bet + HH,
                                         oW, ob, out);
}